// Round 4
// baseline (1092.145 us; speedup 1.0000x reference)
//
#include <hip/hip_runtime.h>

typedef unsigned short u16;
typedef unsigned int   u32;
typedef __attribute__((ext_vector_type(8))) short short8;
typedef __attribute__((ext_vector_type(4))) float f32x4;

#define NTOK 65536
#define IND  768
#define HID  512
#define CBD  256
#define CBS  512

// d_out layout (floats): recon[NTOK*IND], indices-as-float[NTOK], loss[1]
#define OUT_IDX_OFF   ((size_t)NTOK * IND)
#define OUT_LOSS_OFF  (OUT_IDX_OFF + NTOK)

// ws layout (round-4): H and Z stored as SEPARATE hi/lo u16 planes so the
// AMODE1 GEMMs can stage A via global_load_lds DMA (no VALU split).
#define OFF_HH     ((size_t)0)            // H hi u16 [NTOK][HID] = 64MB
#define OFF_HL     ((size_t)67108864)     // H lo u16 [NTOK][HID] = 64MB
#define OFF_ZH     ((size_t)134217728)    // Z hi u16 [NTOK][CBD] = 32MB
#define OFF_ZL     ((size_t)167772160)    // Z lo u16 [NTOK][CBD] = 32MB (ends 199.2MB)
#define OFF_W1H    ((size_t)201326592)    // W1T hi u16 [HID][IND]
#define OFF_W1L    ((size_t)202113024)
#define OFF_W2H    ((size_t)202899456)    // W2T hi u16 [CBD][HID]
#define OFF_W2L    ((size_t)203161600)
#define OFF_CBH    ((size_t)203423744)    // CB  hi u16 [CBS][CBD]
#define OFF_CBL    ((size_t)203685888)
#define OFF_CSQ    ((size_t)203948032)    // c_sq f32 [CBS]
// aliases inside HH region (HH dead after GEMM2 consumes it; all writers below
// run after GEMM2 in stream order)
#define OFF_PART   ((size_t)0)            // partials float4 [NTOK][8]
#define OFF_TABLE  ((size_t)8388608)      // ReconTable f32 [CBS][IND]
#define OFF_ZSQ    ((size_t)9961472)      // zsq f32 [NTOK]
#define OFF_IDX    ((size_t)10223616)     // idx int [NTOK]
#define OFF_FLAGS  ((size_t)10485760)     // flag list int [NTOK]
#define OFF_CNT    ((size_t)10747904)     // [0]=flag_count int, [4]=accum float

__device__ __forceinline__ u16 f2bf(float f) {
    u32 u = __float_as_uint(f);
    return (u16)((u + 0x7fffu + ((u >> 16) & 1u)) >> 16);
}
__device__ __forceinline__ float bf2f(u16 h) {
    return __uint_as_float(((u32)h) << 16);
}

// async global->LDS DMA, 16B per lane. LDS dest = wave-uniform base + lane*16.
__device__ __forceinline__ void dma16(const void* g, void* l) {
    __builtin_amdgcn_global_load_lds(
        (const __attribute__((address_space(1))) u32*)g,
        (__attribute__((address_space(3))) u32*)l, 16, 0, 0);
}

// ---------------------------------------------------------------------------
// codebook split + c_sq : one block per code
// ---------------------------------------------------------------------------
__global__ __launch_bounds__(256) void cbsplit(
    const float* __restrict__ cb, u16* __restrict__ hi, u16* __restrict__ lo,
    float* __restrict__ csq)
{
    int c = blockIdx.x, t = threadIdx.x;
    float v = cb[(size_t)c * CBD + t];
    u16 h = f2bf(v); u16 l = f2bf(v - bf2f(h));
    hi[(size_t)c * CBD + t] = h; lo[(size_t)c * CBD + t] = l;
    __shared__ float red[256];
    red[t] = v * v; __syncthreads();
    for (int s = 128; s; s >>= 1) { if (t < s) red[t] += red[t + s]; __syncthreads(); }
    if (!t) csq[c] = red[0];
}

// ---------------------------------------------------------------------------
// weight transpose+split: W [K,N] fp32 -> WT hi/lo bf16 [N,K]. block per n.
// ---------------------------------------------------------------------------
__global__ __launch_bounds__(256) void wsplit(
    const float* __restrict__ W, u16* __restrict__ hi, u16* __restrict__ lo,
    int K, int N)
{
    int n = blockIdx.x;
    for (int k = threadIdx.x; k < K; k += 256) {
        float v = W[(size_t)k * N + n];
        u16 h = f2bf(v); u16 l = f2bf(v - bf2f(h));
        hi[(size_t)n * K + k] = h; lo[(size_t)n * K + k] = l;
    }
}

// ---------------------------------------------------------------------------
// bf16x3 MFMA GEMM: 128x128 tile, BK=32, 256 thr (4 waves), 4x4 16x16x32 frags
// AMODE 0: A fp32 [M,K] (convert in staging, padded LDS CA=1040)
// AMODE 1: A hi/lo u16 planes [M,K] -> pure DMA staging (CA=1024 linear)
// B always hi/lo u16 planes -> pure DMA staging (stride 1024 linear)
// EPI 0: relu(acc+bias) -> hi/lo planes   EPI 1: acc+bias -> hi/lo planes
// EPI 2: dist = bias[n] - 2*acc; per-row/wave-col top2 -> partials
//
// Round-4: B (and AMODE1 A) staging via global_load_lds (m97 pattern): removes
// the VGPR round-trip + staging VALU that capped MfmaUtil at 31%. DMA dest is
// wave-linear: u16 idx = widx*512 + lane*8 == ku*1024 + n*8 with ku=widx>>1,
// n=(widx&1)*64+lane. Round-3's XCD swizzle + A-pad kept.
// ---------------------------------------------------------------------------
template<int AMODE, int EPI>
__global__ __launch_bounds__(256, 2) void gemm3(
    const float* __restrict__ Af,
    const u16* __restrict__ Ahi, const u16* __restrict__ Alo,
    const u16* __restrict__ Bhi, const u16* __restrict__ Blo,
    const float* __restrict__ bias,
    u16* __restrict__ Ohi, u16* __restrict__ Olo, float* __restrict__ Opart,
    int M, int N, int K)
{
    constexpr int CA = (AMODE == 0) ? 1040 : 1024;   // A chunk stride (u16)
    __shared__ u16 lds[8 * 1040 + 8 * 1024];
    u16* sAh = lds;
    u16* sAl = lds + 4 * CA;
    u16* sBh = lds + 8 * CA;
    u16* sBl = lds + 8 * CA + 4096;
    const int tid  = threadIdx.x;

    // XCD-aware bijective remap (all grids here have nwg % 8 == 0)
    const int nwg = gridDim.x * gridDim.y;
    const int hw  = blockIdx.y * gridDim.x + blockIdx.x;
    const int logical = (hw & 7) * (nwg >> 3) + (hw >> 3);
    const int bx = logical % gridDim.x;
    const int by = logical / gridDim.x;

    const int m0 = by * 128, n0 = bx * 128;
    const int w = tid >> 6, lane = tid & 63, quad = lane >> 4, l15 = lane & 15;
    const int wm = (w & 1) * 64, wn = (w >> 1) * 64;

    f32x4 acc[4][4] = {};

    for (int k0 = 0; k0 < K; k0 += 32) {
        __syncthreads();
        // B planes: 16 wave-loads of 1KB (4 per wave), pure DMA
        #pragma unroll
        for (int g = 0; g < 4; ++g) {
            int gi = w * 4 + g;            // 0..15
            int widx = gi & 7;
            const u16* src = ((gi & 8) ? Blo : Bhi)
                + (size_t)(n0 + ((widx & 1) << 6) + lane) * K + k0 + ((widx >> 1) << 3);
            u16* dst = ((gi & 8) ? sBl : sBh) + widx * 512;
            dma16(src, dst);
        }
        if (AMODE == 1) {
            // A planes: pure DMA, same mapping
            #pragma unroll
            for (int g = 0; g < 4; ++g) {
                int gi = w * 4 + g;
                int widx = gi & 7;
                const u16* src = ((gi & 8) ? Alo : Ahi)
                    + (size_t)(m0 + ((widx & 1) << 6) + lane) * K + k0 + ((widx >> 1) << 3);
                u16* dst = ((gi & 8) ? sAl : sAh) + widx * 512;
                dma16(src, dst);
            }
        } else {
            // A fp32 -> bf16 hi/lo convert staging (overlaps with B DMA)
            #pragma unroll
            for (int s = 0; s < 4; ++s) {
                int slot = tid + s * 256;
                int m = slot >> 3, kg = (slot & 7) << 2;
                int c = kg >> 3, off = kg & 7;
                float4 v = *(const float4*)(Af + (size_t)(m0 + m) * K + k0 + kg);
                u16 h0 = f2bf(v.x), h1 = f2bf(v.y), h2 = f2bf(v.z), h3 = f2bf(v.w);
                ushort4 hv = {h0, h1, h2, h3};
                ushort4 lv = {f2bf(v.x - bf2f(h0)), f2bf(v.y - bf2f(h1)),
                              f2bf(v.z - bf2f(h2)), f2bf(v.w - bf2f(h3))};
                *(ushort4*)&sAh[c * CA + m * 8 + off] = hv;
                *(ushort4*)&sAl[c * CA + m * 8 + off] = lv;
            }
        }
        __syncthreads();

        short8 ah[4], al[4], bh[4], bl[4];
        #pragma unroll
        for (int i = 0; i < 4; ++i) {
            int ar = wm + i * 16 + l15;
            int br = wn + i * 16 + l15;
            ah[i] = *(const short8*)&sAh[quad * CA + ar * 8];
            al[i] = *(const short8*)&sAl[quad * CA + ar * 8];
            bh[i] = *(const short8*)&sBh[quad * 1024 + br * 8];
            bl[i] = *(const short8*)&sBl[quad * 1024 + br * 8];
        }
        #pragma unroll
        for (int i = 0; i < 4; ++i)
            #pragma unroll
            for (int j = 0; j < 4; ++j) {
                acc[i][j] = __builtin_amdgcn_mfma_f32_16x16x32_bf16(ah[i], bh[j], acc[i][j], 0, 0, 0);
                acc[i][j] = __builtin_amdgcn_mfma_f32_16x16x32_bf16(ah[i], bl[j], acc[i][j], 0, 0, 0);
                acc[i][j] = __builtin_amdgcn_mfma_f32_16x16x32_bf16(al[i], bh[j], acc[i][j], 0, 0, 0);
            }
    }

    // epilogue. C/D layout: col = n-tile + l15, row = m-tile + quad*4 + r
    if (EPI <= 1) {
        float bn[4];
        #pragma unroll
        for (int j = 0; j < 4; ++j) bn[j] = bias[n0 + wn + j * 16 + l15];
        #pragma unroll
        for (int i = 0; i < 4; ++i)
            #pragma unroll
            for (int r = 0; r < 4; ++r) {
                int row = m0 + wm + i * 16 + quad * 4 + r;
                #pragma unroll
                for (int j = 0; j < 4; ++j) {
                    float v = acc[i][j][r] + bn[j];
                    if (EPI == 0) v = fmaxf(v, 0.f);
                    u16 h = f2bf(v); u16 l = f2bf(v - bf2f(h));
                    size_t o = (size_t)row * N + n0 + wn + j * 16 + l15;
                    Ohi[o] = h; Olo[o] = l;
                }
            }
    } else {
        float cs[4]; int cidx[4];
        #pragma unroll
        for (int j = 0; j < 4; ++j) {
            cidx[j] = n0 + wn + j * 16 + l15;
            cs[j] = bias[cidx[j]];
        }
        const int nparts = gridDim.x * 2;
        const int pslot  = bx * 2 + (w >> 1);   // distinct per wave-column!
        #pragma unroll
        for (int i = 0; i < 4; ++i)
            #pragma unroll
            for (int r = 0; r < 4; ++r) {
                int row = m0 + wm + i * 16 + quad * 4 + r;
                float d1 = 3.4e38f, d2 = 3.4e38f; int i1 = 0x7fffffff;
                #pragma unroll
                for (int j = 0; j < 4; ++j) {
                    float v = fmaf(-2.0f, acc[i][j][r], cs[j]);
                    if (v < d1) { d2 = d1; d1 = v; i1 = cidx[j]; }
                    else d2 = fminf(d2, v);
                }
                #pragma unroll
                for (int mm = 1; mm < 16; mm <<= 1) {
                    float od1 = __shfl_xor(d1, mm, 64);
                    float od2 = __shfl_xor(d2, mm, 64);
                    int   oi1 = __shfl_xor(i1, mm, 64);
                    if (od1 < d1 || (od1 == d1 && oi1 < i1)) { d2 = fminf(d1, od2); d1 = od1; i1 = oi1; }
                    else d2 = fminf(d2, od1);
                }
                if (l15 == 0) {
                    float4 o = {d1, d2, __int_as_float(i1), 0.f};
                    *(float4*)&Opart[((size_t)row * nparts + pslot) * 4] = o;
                }
            }
    }
}

// ---------------------------------------------------------------------------
// zsq from hi/lo Z planes
// ---------------------------------------------------------------------------
__global__ __launch_bounds__(256) void zsq_pk(
    const u16* __restrict__ Zh, const u16* __restrict__ Zl, float* __restrict__ zsq)
{
    int tok = blockIdx.x * 4 + (threadIdx.x >> 6);
    int lane = threadIdx.x & 63;
    ushort4 uh = *(const ushort4*)(Zh + (size_t)tok * CBD + lane * 4);
    ushort4 ul = *(const ushort4*)(Zl + (size_t)tok * CBD + lane * 4);
    float z0 = bf2f(uh.x) + bf2f(ul.x);
    float z1 = bf2f(uh.y) + bf2f(ul.y);
    float z2 = bf2f(uh.z) + bf2f(ul.z);
    float z3 = bf2f(uh.w) + bf2f(ul.w);
    float s = z0 * z0 + z1 * z1 + z2 * z2 + z3 * z3;
    #pragma unroll
    for (int off = 32; off; off >>= 1) s += __shfl_down(s, off, 64);
    if (!lane) zsq[tok] = s;
}

// ---------------------------------------------------------------------------
// combine per-slot top2 partials (8 per token) -> idx, flags, commit sum
// ---------------------------------------------------------------------------
__global__ __launch_bounds__(256) void vq_reduce(
    const float* __restrict__ part, const float* __restrict__ zsq,
    float* __restrict__ out_idx, int* __restrict__ idx_i,
    int* __restrict__ cnt, float* __restrict__ accum, int* __restrict__ flags)
{
    int tok = blockIdx.x * 256 + threadIdx.x;
    float d1 = 3.4e38f, d2 = 3.4e38f; int i1 = 0x7fffffff;
    #pragma unroll
    for (int nb = 0; nb < 8; ++nb) {
        float4 p = *(const float4*)&part[((size_t)tok * 8 + nb) * 4];
        float pd1 = p.x, pd2 = p.y; int pi1 = __float_as_int(p.z);
        if (pd1 < d1 || (pd1 == d1 && pi1 < i1)) { d2 = fminf(d1, pd2); d1 = pd1; i1 = pi1; }
        else d2 = fminf(d2, pd1);
    }
    out_idx[tok] = (float)i1;
    idx_i[tok] = i1;
    if (d2 - d1 < 0.01f) {
        int p = atomicAdd(cnt, 1);
        if (p >= 0 && p < NTOK) flags[p] = tok;
    }
    float c = zsq[tok] + d1;      // ||z||^2 + c_sq - 2 dot = ||z - q||^2
    __shared__ float red[256];
    red[threadIdx.x] = c; __syncthreads();
    for (int s = 128; s; s >>= 1) { if (threadIdx.x < s) red[threadIdx.x] += red[threadIdx.x + s]; __syncthreads(); }
    if (!threadIdx.x) atomicAdd(accum, red[0]);
}

// ---------------------------------------------------------------------------
// exact fp32 recompute of argmin for near-tie tokens.
// Round-4: wall time == ONE batch-iteration latency (nb <= grid), and round-3
// was 97% stalled on ~4-deep serial W-streams (VALUBusy 1%). Now W1/W2 stream
// through a 2x8KB double-buffered LDS window via global_load_lds (chunk c+1
// issued before computing chunk c; 1 barrier/chunk) -> wide coalesced DMA,
// latency hidden under FMAs. csq staged to LDS. dist phase verbatim.
// LDS 67KB -> 2 blocks/CU.
// ---------------------------------------------------------------------------
__global__ __launch_bounds__(256) void fixup(
    const int* __restrict__ cnt, const int* __restrict__ flags,
    const float* __restrict__ x, const float* __restrict__ W1, const float* __restrict__ b1,
    const float* __restrict__ W2, const float* __restrict__ b2,
    const float* __restrict__ cb, const float* __restrict__ csq,
    int* __restrict__ idx_i, float* __restrict__ out_idx)
{
    __shared__ float xs[8][IND];      // 24KB
    __shared__ float hs[8][HID];      // 16KB
    __shared__ float zs[8][CBD];      //  8KB
    __shared__ float wbuf[2][2048];   // 16KB W-stream double buffer
    __shared__ float csq_s[CBS];      //  2KB
    __shared__ float bd_s[4][8];
    __shared__ int   bi_s[4][8];
    __shared__ int   tok_s[8];

    int n = cnt[0]; if (n > NTOK) n = NTOK; if (n < 0) n = 0;
    const int t = threadIdx.x;
    const int w = t >> 6, lane = t & 63;
    const int nb = (n + 7) >> 3;

    if (t < 128) *(float4*)&csq_s[t * 4] = *(const float4*)(csq + t * 4);

    // W1 chunk = 4 rows x 512 = 8KB (192 chunks); W2 chunk = 8 rows x 256 (64)
    auto stage_w1 = [&](int ch, int p) {
        #pragma unroll
        for (int g = 0; g < 2; ++g) {
            int gi = w * 2 + g;   // 0..7, 1KB each
            dma16(W1 + (size_t)ch * 2048 + gi * 256 + lane * 4, &wbuf[p][gi * 256]);
        }
    };
    auto stage_w2 = [&](int ch, int p) {
        #pragma unroll
        for (int g = 0; g < 2; ++g) {
            int gi = w * 2 + g;
            dma16(W2 + (size_t)ch * 2048 + gi * 256 + lane * 4, &wbuf[p][gi * 256]);
        }
    };

    for (int ib = blockIdx.x; ib < nb; ib += gridDim.x) {
        const int base = ib * 8;
        __syncthreads();                       // prev-iter readers of tok_s/xs done
        if (t < 8) {
            int fi = base + t; if (fi > n - 1) fi = n - 1;
            tok_s[t] = flags[fi];
        }
        __syncthreads();

        stage_w1(0, 0);                        // prologue DMA (xs-independent)

        // stage 8 x-rows: 1536 float4, 6 per thread
        #pragma unroll
        for (int s = 0; s < 6; ++s) {
            int slot = t + s * 256;
            int tt = slot / 192, c4 = slot - tt * 192;
            *(float4*)&xs[tt][c4 * 4] =
                *(const float4*)(x + (size_t)tok_s[tt] * IND + c4 * 4);
        }

        // ---- h = relu(x @ W1 + b1): thread owns 4 tokens x 4 cols ----
        {
            const int tg = t >> 7;
            const int j0 = (t & 127) * 4;
            float a[4][4];
            float4 bb = *(const float4*)(b1 + j0);
            #pragma unroll
            for (int ti = 0; ti < 4; ++ti) {
                a[ti][0] = bb.x; a[ti][1] = bb.y; a[ti][2] = bb.z; a[ti][3] = bb.w;
            }
            for (int ch = 0; ch < 192; ++ch) {
                __syncthreads();               // chunk ch staged; prev compute done
                if (ch + 1 < 192) stage_w1(ch + 1, (ch + 1) & 1);
                float4 xv[4];
                #pragma unroll
                for (int ti = 0; ti < 4; ++ti)
                    xv[ti] = *(const float4*)&xs[tg * 4 + ti][ch * 4];
                #pragma unroll
                for (int kk = 0; kk < 4; ++kk) {
                    float4 wv = *(const float4*)&wbuf[ch & 1][kk * 512 + j0];
                    #pragma unroll
                    for (int ti = 0; ti < 4; ++ti) {
                        float xk = (kk == 0) ? xv[ti].x : (kk == 1) ? xv[ti].y
                                 : (kk == 2) ? xv[ti].z : xv[ti].w;
                        a[ti][0] = fmaf(xk, wv.x, a[ti][0]);
                        a[ti][1] = fmaf(xk, wv.y, a[ti][1]);
                        a[ti][2] = fmaf(xk, wv.z, a[ti][2]);
                        a[ti][3] = fmaf(xk, wv.w, a[ti][3]);
                    }
                }
            }
            #pragma unroll
            for (int ti = 0; ti < 4; ++ti) {
                float4 o = {fmaxf(a[ti][0], 0.f), fmaxf(a[ti][1], 0.f),
                            fmaxf(a[ti][2], 0.f), fmaxf(a[ti][3], 0.f)};
                *(float4*)&hs[tg * 4 + ti][j0] = o;
            }
        }
        __syncthreads();

        // ---- z = h @ W2 + b2: thread owns 2 tokens x 4 cols ----
        {
            const int tg = t >> 6;
            const int c0 = (t & 63) * 4;
            float az[2][4];
            float4 bz = *(const float4*)(b2 + c0);
            #pragma unroll
            for (int ti = 0; ti < 2; ++ti) {
                az[ti][0] = bz.x; az[ti][1] = bz.y; az[ti][2] = bz.z; az[ti][3] = bz.w;
            }
            stage_w2(0, 0);
            for (int ch = 0; ch < 64; ++ch) {
                __syncthreads();
                if (ch + 1 < 64) stage_w2(ch + 1, (ch + 1) & 1);
                #pragma unroll
                for (int k4 = 0; k4 < 2; ++k4) {
                    float4 hv[2];
                    #pragma unroll
                    for (int ti = 0; ti < 2; ++ti)
                        hv[ti] = *(const float4*)&hs[tg * 2 + ti][ch * 8 + k4 * 4];
                    #pragma unroll
                    for (int kk = 0; kk < 4; ++kk) {
                        float4 wv = *(const float4*)&wbuf[ch & 1][(k4 * 4 + kk) * 256 + c0];
                        #pragma unroll
                        for (int ti = 0; ti < 2; ++ti) {
                            float hk = (kk == 0) ? hv[ti].x : (kk == 1) ? hv[ti].y
                                     : (kk == 2) ? hv[ti].z : hv[ti].w;
                            az[ti][0] = fmaf(hk, wv.x, az[ti][0]);
                            az[ti][1] = fmaf(hk, wv.y, az[ti][1]);
                            az[ti][2] = fmaf(hk, wv.z, az[ti][2]);
                            az[ti][3] = fmaf(hk, wv.w, az[ti][3]);
                        }
                    }
                }
            }
            #pragma unroll
            for (int ti = 0; ti < 2; ++ti) {
                float4 o = {az[ti][0], az[ti][1], az[ti][2], az[ti][3]};
                *(float4*)&zs[tg * 2 + ti][c0] = o;
            }
        }
        __syncthreads();

        // ---- dists + argmin: wave wv owns codes [wv*128, +128) ----
        {
            const int wv = t >> 6, l = t & 63;
            float4 zv[8];
            #pragma unroll
            for (int tt = 0; tt < 8; ++tt) zv[tt] = *(const float4*)&zs[tt][l * 4];
            float bd[8]; int bi[8];
            #pragma unroll
            for (int tt = 0; tt < 8; ++tt) { bd[tt] = 3.4e38f; bi[tt] = 0x7fffffff; }
            for (int cc = 0; cc < 128; ++cc) {
                int c = wv * 128 + cc;
                float4 cv = *(const float4*)(cb + (size_t)c * CBD + l * 4);
                float cs = csq_s[c];
                #pragma unroll
                for (int tt = 0; tt < 8; ++tt) {
                    float p = zv[tt].x * cv.x + zv[tt].y * cv.y + zv[tt].z * cv.z + zv[tt].w * cv.w;
                    #pragma unroll
                    for (int mm = 32; mm; mm >>= 1) p += __shfl_xor(p, mm, 64);
                    float d = cs - 2.f * p;
                    if (d < bd[tt]) { bd[tt] = d; bi[tt] = c; }  // ascending c -> keeps first
                }
            }
            if (l == 0) {
                #pragma unroll
                for (int tt = 0; tt < 8; ++tt) { bd_s[wv][tt] = bd[tt]; bi_s[wv][tt] = bi[tt]; }
            }
        }
        __syncthreads();

        if (t < 8) {
            const int tt = t;
            float d = bd_s[0][tt]; int i = bi_s[0][tt];
            #pragma unroll
            for (int wv = 1; wv < 4; ++wv) {
                float od = bd_s[wv][tt]; int oi = bi_s[wv][tt];
                if (od < d || (od == d && oi < i)) { d = od; i = oi; }
            }
            if (base + tt < n) {
                int tok = tok_s[tt];
                idx_i[tok] = i; out_idx[tok] = (float)i;
            }
        }
    }
}

// ---------------------------------------------------------------------------
// ReconTable = decoder(codebook): one block per code
// ---------------------------------------------------------------------------
__global__ __launch_bounds__(256) void table_pre(
    const float* __restrict__ cb, const float* __restrict__ W3,
    const float* __restrict__ b3, const float* __restrict__ W4,
    const float* __restrict__ b4, float* __restrict__ table)
{
    __shared__ float crow[CBD];
    __shared__ float h2[HID];
    const int c = blockIdx.x;
    const int t = threadIdx.x;
    crow[t] = cb[(size_t)c * CBD + t];
    __syncthreads();
    #pragma unroll
    for (int s = 0; s < 2; ++s) {
        int j = t + s * 256;
        float acc = b3[j];
        for (int k = 0; k < CBD; ++k) acc = fmaf(crow[k], W3[(size_t)k * HID + j], acc);
        h2[j] = fmaxf(acc, 0.f);
    }
    __syncthreads();
    #pragma unroll
    for (int s = 0; s < 3; ++s) {
        int j = t + s * 256;
        float acc = b4[j];
        for (int k = 0; k < HID; ++k) acc = fmaf(h2[k], W4[(size_t)k * IND + j], acc);
        table[(size_t)c * IND + j] = acc;
    }
}

// ---------------------------------------------------------------------------
// recon gather
// ---------------------------------------------------------------------------
__global__ __launch_bounds__(256) void gather_kernel(
    const int* __restrict__ idx, const float* __restrict__ table,
    float* __restrict__ out)
{
    unsigned i = blockIdx.x * 256u + threadIdx.x;   // float4 index, total NTOK*192
    unsigned tok = i / 192u;
    unsigned c = i - tok * 192u;
    int id = idx[tok];
    ((float4*)out)[i] = ((const float4*)table)[(size_t)id * 192 + c];
}

__global__ void finalize_kernel(const float* __restrict__ accum,
                                float* __restrict__ out_loss)
{
    out_loss[0] = accum[0] * (1.0f / 16777216.0f);   // mean over NTOK*CBD
}

// ---------------------------------------------------------------------------
extern "C" void kernel_launch(void* const* d_in, const int* in_sizes, int n_in,
                              void* d_out, int out_size, void* d_ws, size_t ws_size,
                              hipStream_t stream) {
    const float* x  = (const float*)d_in[0];
    const float* W1 = (const float*)d_in[1];
    const float* b1 = (const float*)d_in[2];
    const float* W2 = (const float*)d_in[3];
    const float* b2 = (const float*)d_in[4];
    const float* cb = (const float*)d_in[5];
    const float* W3 = (const float*)d_in[6];
    const float* b3 = (const float*)d_in[7];
    const float* W4 = (const float*)d_in[8];
    const float* b4 = (const float*)d_in[9];

    char* ws = (char*)d_ws;
    u16*  Hh    = (u16*)(ws + OFF_HH);
    u16*  Hl    = (u16*)(ws + OFF_HL);
    u16*  Zh    = (u16*)(ws + OFF_ZH);
    u16*  Zl    = (u16*)(ws + OFF_ZL);
    u16*  W1h   = (u16*)(ws + OFF_W1H);
    u16*  W1l   = (u16*)(ws + OFF_W1L);
    u16*  W2h   = (u16*)(ws + OFF_W2H);
    u16*  W2l   = (u16*)(ws + OFF_W2L);
    u16*  CBh   = (u16*)(ws + OFF_CBH);
    u16*  CBl   = (u16*)(ws + OFF_CBL);
    float* csq  = (float*)(ws + OFF_CSQ);
    float* part = (float*)(ws + OFF_PART);
    float* table = (float*)(ws + OFF_TABLE);
    float* zsq  = (float*)(ws + OFF_ZSQ);
    int*   idx_i = (int*)(ws + OFF_IDX);
    int*   flags = (int*)(ws + OFF_FLAGS);
    int*   cnt   = (int*)(ws + OFF_CNT);
    float* accum = (float*)(ws + OFF_CNT + 4);

    float* out      = (float*)d_out;
    float* out_idx  = out + OUT_IDX_OFF;
    float* out_loss = out + OUT_LOSS_OFF;

    cbsplit<<<CBS, 256, 0, stream>>>(cb, CBh, CBl, csq);
    wsplit<<<HID, 256, 0, stream>>>(W1, W1h, W1l, IND, HID);   // W1T [512][768]
    wsplit<<<CBD, 256, 0, stream>>>(W2, W2h, W2l, HID, CBD);   // W2T [256][512]

    // h = relu(x @ W1 + b1) -> hi/lo planes
    gemm3<0, 0><<<dim3(HID / 128, NTOK / 128), 256, 0, stream>>>(
        x, (const u16*)nullptr, (const u16*)nullptr, W1h, W1l, b1,
        Hh, Hl, (float*)nullptr, NTOK, HID, IND);
    // z = h @ W2 + b2 -> hi/lo planes
    gemm3<1, 1><<<dim3(CBD / 128, NTOK / 128), 256, 0, stream>>>(
        (const float*)nullptr, Hh, Hl, W2h, W2l, b2,
        Zh, Zl, (float*)nullptr, NTOK, CBD, HID);

    // HH region is dead from here on; zero cnt/accum AFTER GEMM2 consumed Hh
    hipMemsetAsync(cnt, 0, 8, stream);

    zsq_pk<<<NTOK / 4, 256, 0, stream>>>(Zh, Zl, zsq);

    // dists top-2 partials: dist = c_sq - 2 * (z . c)
    gemm3<1, 2><<<dim3(CBS / 128, NTOK / 128), 256, 0, stream>>>(
        (const float*)nullptr, Zh, Zl, CBh, CBl, csq,
        (u16*)nullptr, (u16*)nullptr, part, NTOK, CBS, CBD);

    table_pre<<<CBS, 256, 0, stream>>>(cb, W3, b3, W4, b4, table);

    vq_reduce<<<NTOK / 256, 256, 0, stream>>>(part, zsq, out_idx, idx_i, cnt, accum, flags);

    fixup<<<1024, 256, 0, stream>>>(cnt, flags, x, W1, b1, W2, b2, cb, csq, idx_i, out_idx);

    gather_kernel<<<(NTOK * (IND / 4)) / 256, 256, 0, stream>>>(idx_i, table, out);

    finalize_kernel<<<1, 1, 0, stream>>>(accum, out_loss);
}

// Round 5
// 972.893 us; speedup vs baseline: 1.1226x; 1.1226x over previous
//
#include <hip/hip_runtime.h>

typedef unsigned short u16;
typedef unsigned int   u32;
typedef __attribute__((ext_vector_type(8))) short short8;
typedef __attribute__((ext_vector_type(4))) float f32x4;

#define NTOK 65536
#define IND  768
#define HID  512
#define CBD  256
#define CBS  512

// d_out layout (floats): recon[NTOK*IND], indices-as-float[NTOK], loss[1]
#define OUT_IDX_OFF   ((size_t)NTOK * IND)
#define OUT_LOSS_OFF  (OUT_IDX_OFF + NTOK)

// ws byte offsets (round-3 layout: packed u32 H/Z planes)
#define OFF_H      ((size_t)0)            // Hpack u32 [NTOK][HID]  = 134,217,728 B
#define OFF_Z      ((size_t)134217728)    // Zpack u32 [NTOK][CBD]  =  67,108,864 B
#define OFF_W1H    ((size_t)201326592)    // W1T hi u16 [HID][IND]
#define OFF_W1L    ((size_t)202113024)
#define OFF_W2H    ((size_t)202899456)    // W2T hi u16 [CBD][HID]
#define OFF_W2L    ((size_t)203161600)
#define OFF_CBH    ((size_t)203423744)    // CB  hi u16 [CBS][CBD]
#define OFF_CBL    ((size_t)203685888)
#define OFF_CSQ    ((size_t)203948032)    // c_sq f32 [CBS]
// aliases inside H region (H dead after GEMM2 consumes it)
#define OFF_PART   ((size_t)0)            // partials float4 [NTOK][8]
#define OFF_TABLE  ((size_t)8388608)      // ReconTable f32 [CBS][IND]
#define OFF_ZSQ    ((size_t)9961472)      // zsq f32 [NTOK]
#define OFF_IDX    ((size_t)10223616)     // idx int [NTOK]
#define OFF_FLAGS  ((size_t)10485760)     // flag list int [NTOK]
#define OFF_CNT    ((size_t)10747904)     // [0]=flag_count int, [4]=accum float

__device__ __forceinline__ u16 f2bf(float f) {
    u32 u = __float_as_uint(f);
    return (u16)((u + 0x7fffu + ((u >> 16) & 1u)) >> 16);
}
__device__ __forceinline__ float bf2f(u16 h) {
    return __uint_as_float(((u32)h) << 16);
}

// ---------------------------------------------------------------------------
// codebook split + c_sq : one block per code
// ---------------------------------------------------------------------------
__global__ __launch_bounds__(256) void cbsplit(
    const float* __restrict__ cb, u16* __restrict__ hi, u16* __restrict__ lo,
    float* __restrict__ csq)
{
    int c = blockIdx.x, t = threadIdx.x;
    float v = cb[(size_t)c * CBD + t];
    u16 h = f2bf(v); u16 l = f2bf(v - bf2f(h));
    hi[(size_t)c * CBD + t] = h; lo[(size_t)c * CBD + t] = l;
    __shared__ float red[256];
    red[t] = v * v; __syncthreads();
    for (int s = 128; s; s >>= 1) { if (t < s) red[t] += red[t + s]; __syncthreads(); }
    if (!t) csq[c] = red[0];
}

// ---------------------------------------------------------------------------
// weight transpose+split: W [K,N] fp32 -> WT hi/lo bf16 [N,K]. block per n.
// ---------------------------------------------------------------------------
__global__ __launch_bounds__(256) void wsplit(
    const float* __restrict__ W, u16* __restrict__ hi, u16* __restrict__ lo,
    int K, int N)
{
    int n = blockIdx.x;
    for (int k = threadIdx.x; k < K; k += 256) {
        float v = W[(size_t)k * N + n];
        u16 h = f2bf(v); u16 l = f2bf(v - bf2f(h));
        hi[(size_t)n * K + k] = h; lo[(size_t)n * K + k] = l;
    }
}

// ---------------------------------------------------------------------------
// bf16x3 MFMA GEMM (round-3 verified version, verbatim): 128x128 tile, BK=32,
// chunk-major LDS [chunk=k/8][row][8u16] stride 1040 (conflict-reduced),
// bijective XCD swizzle. Round-4's DMA staging reverted: its per-lane
// row-gather source (64 cache lines/instr) regressed all three instances.
// ---------------------------------------------------------------------------
#define CHS 1040   // u16 per chunk block: 128 rows * 8 + 8 pad
#define PLN (4 * CHS)

template<int AMODE, int EPI>
__global__ __launch_bounds__(256, 2) void gemm3(
    const float* __restrict__ Af, const u32* __restrict__ Apk,
    const u16* __restrict__ Bhi, const u16* __restrict__ Blo,
    const float* __restrict__ bias,
    u32* __restrict__ Opk, float* __restrict__ Opart,
    int M, int N, int K)
{
    __shared__ u16 lds[4 * PLN];              // 32.5 KB: Ahi, Alo, Bhi, Blo
    u16* sAh = lds;
    u16* sAl = lds + PLN;
    u16* sBh = lds + 2 * PLN;
    u16* sBl = lds + 3 * PLN;
    const int tid  = threadIdx.x;

    // XCD-aware bijective remap (all grids here have nwg % 8 == 0)
    const int nwg = gridDim.x * gridDim.y;
    const int hw  = blockIdx.y * gridDim.x + blockIdx.x;
    const int logical = (hw & 7) * (nwg >> 3) + (hw >> 3);
    const int bx = logical % gridDim.x;
    const int by = logical / gridDim.x;

    const int m0 = by * 128, n0 = bx * 128;
    const int w = tid >> 6, lane = tid & 63, quad = lane >> 4, l15 = lane & 15;
    const int wm = (w & 1) * 64, wn = (w >> 1) * 64;

    f32x4 acc[4][4] = {};

    for (int k0 = 0; k0 < K; k0 += 32) {
        __syncthreads();
        if (AMODE == 0) {
            #pragma unroll
            for (int s = 0; s < 4; ++s) {
                int slot = tid + s * 256;
                int m = slot >> 3, kg = (slot & 7) << 2;
                int c = kg >> 3, off = kg & 7;
                float4 v = *(const float4*)(Af + (size_t)(m0 + m) * K + k0 + kg);
                u16 h0 = f2bf(v.x), h1 = f2bf(v.y), h2 = f2bf(v.z), h3 = f2bf(v.w);
                ushort4 hv = {h0, h1, h2, h3};
                ushort4 lv = {f2bf(v.x - bf2f(h0)), f2bf(v.y - bf2f(h1)),
                              f2bf(v.z - bf2f(h2)), f2bf(v.w - bf2f(h3))};
                *(ushort4*)&sAh[c * CHS + m * 8 + off] = hv;
                *(ushort4*)&sAl[c * CHS + m * 8 + off] = lv;
            }
        } else {
            #pragma unroll
            for (int s = 0; s < 4; ++s) {
                int slot = tid + s * 256;
                int m = slot >> 3, ke = (slot & 7) << 2;   // 4 elems per uint4
                int c = ke >> 3, off = ke & 7;
                uint4 u = *(const uint4*)(Apk + (size_t)(m0 + m) * K + k0 + ke);
                ushort4 hv = {(u16)(u.x & 0xffff), (u16)(u.y & 0xffff),
                              (u16)(u.z & 0xffff), (u16)(u.w & 0xffff)};
                ushort4 lv = {(u16)(u.x >> 16), (u16)(u.y >> 16),
                              (u16)(u.z >> 16), (u16)(u.w >> 16)};
                *(ushort4*)&sAh[c * CHS + m * 8 + off] = hv;
                *(ushort4*)&sAl[c * CHS + m * 8 + off] = lv;
            }
        }
        // B planes [N,K] bf16 -> LDS (8 k-elems per uint4 = exactly one chunk row)
        #pragma unroll
        for (int s = 0; s < 4; ++s) {
            int slot = tid + s * 256;                 // 1024 slots, 512 per plane
            int n = (slot & 511) >> 2, ku = slot & 3; // ku = chunk
            const u16* src = (slot < 512) ? Bhi : Blo;
            u16* dst = (slot < 512) ? sBh : sBl;
            uint4 u = *(const uint4*)(src + (size_t)(n0 + n) * K + k0 + ku * 8);
            *(uint4*)&dst[ku * CHS + n * 8] = u;
        }
        __syncthreads();

        short8 ah[4], al[4], bh[4], bl[4];
        const int kc = quad * CHS;
        #pragma unroll
        for (int i = 0; i < 4; ++i) {
            int ar = wm + i * 16 + l15;
            int br = wn + i * 16 + l15;
            ah[i] = *(const short8*)&sAh[kc + ar * 8];
            al[i] = *(const short8*)&sAl[kc + ar * 8];
            bh[i] = *(const short8*)&sBh[kc + br * 8];
            bl[i] = *(const short8*)&sBl[kc + br * 8];
        }
        #pragma unroll
        for (int i = 0; i < 4; ++i)
            #pragma unroll
            for (int j = 0; j < 4; ++j) {
                acc[i][j] = __builtin_amdgcn_mfma_f32_16x16x32_bf16(ah[i], bh[j], acc[i][j], 0, 0, 0);
                acc[i][j] = __builtin_amdgcn_mfma_f32_16x16x32_bf16(ah[i], bl[j], acc[i][j], 0, 0, 0);
                acc[i][j] = __builtin_amdgcn_mfma_f32_16x16x32_bf16(al[i], bh[j], acc[i][j], 0, 0, 0);
            }
    }

    // epilogue. C/D layout: col = n-tile + l15, row = m-tile + quad*4 + r
    if (EPI <= 1) {
        float bn[4];
        #pragma unroll
        for (int j = 0; j < 4; ++j) bn[j] = bias[n0 + wn + j * 16 + l15];
        #pragma unroll
        for (int i = 0; i < 4; ++i)
            #pragma unroll
            for (int r = 0; r < 4; ++r) {
                int row = m0 + wm + i * 16 + quad * 4 + r;
                #pragma unroll
                for (int j = 0; j < 4; ++j) {
                    float v = acc[i][j][r] + bn[j];
                    if (EPI == 0) v = fmaxf(v, 0.f);
                    u16 h = f2bf(v); u16 l = f2bf(v - bf2f(h));
                    Opk[(size_t)row * N + n0 + wn + j * 16 + l15] = (u32)h | ((u32)l << 16);
                }
            }
    } else {
        float cs[4]; int cidx[4];
        #pragma unroll
        for (int j = 0; j < 4; ++j) {
            cidx[j] = n0 + wn + j * 16 + l15;
            cs[j] = bias[cidx[j]];
        }
        const int nparts = gridDim.x * 2;
        const int pslot  = bx * 2 + (w >> 1);   // distinct per wave-column!
        #pragma unroll
        for (int i = 0; i < 4; ++i)
            #pragma unroll
            for (int r = 0; r < 4; ++r) {
                int row = m0 + wm + i * 16 + quad * 4 + r;
                float d1 = 3.4e38f, d2 = 3.4e38f; int i1 = 0x7fffffff;
                #pragma unroll
                for (int j = 0; j < 4; ++j) {
                    float v = fmaf(-2.0f, acc[i][j][r], cs[j]);
                    if (v < d1) { d2 = d1; d1 = v; i1 = cidx[j]; }
                    else d2 = fminf(d2, v);
                }
                #pragma unroll
                for (int mm = 1; mm < 16; mm <<= 1) {
                    float od1 = __shfl_xor(d1, mm, 64);
                    float od2 = __shfl_xor(d2, mm, 64);
                    int   oi1 = __shfl_xor(i1, mm, 64);
                    if (od1 < d1 || (od1 == d1 && oi1 < i1)) { d2 = fminf(d1, od2); d1 = od1; i1 = oi1; }
                    else d2 = fminf(d2, od1);
                }
                if (l15 == 0) {
                    float4 o = {d1, d2, __int_as_float(i1), 0.f};
                    *(float4*)&Opart[((size_t)row * nparts + pslot) * 4] = o;
                }
            }
    }
}

// ---------------------------------------------------------------------------
// zsq from packed z
// ---------------------------------------------------------------------------
__global__ __launch_bounds__(256) void zsq_pk(
    const u32* __restrict__ Zpk, float* __restrict__ zsq)
{
    int tok = blockIdx.x * 4 + (threadIdx.x >> 6);
    int lane = threadIdx.x & 63;
    uint4 u = *(const uint4*)(Zpk + (size_t)tok * CBD + lane * 4);
    float z0 = bf2f((u16)(u.x & 0xffff)) + bf2f((u16)(u.x >> 16));
    float z1 = bf2f((u16)(u.y & 0xffff)) + bf2f((u16)(u.y >> 16));
    float z2 = bf2f((u16)(u.z & 0xffff)) + bf2f((u16)(u.z >> 16));
    float z3 = bf2f((u16)(u.w & 0xffff)) + bf2f((u16)(u.w >> 16));
    float s = z0 * z0 + z1 * z1 + z2 * z2 + z3 * z3;
    #pragma unroll
    for (int off = 32; off; off >>= 1) s += __shfl_down(s, off, 64);
    if (!lane) zsq[tok] = s;
}

// ---------------------------------------------------------------------------
// combine per-slot top2 partials (8 per token) -> idx, flags, commit sum
// ---------------------------------------------------------------------------
__global__ __launch_bounds__(256) void vq_reduce(
    const float* __restrict__ part, const float* __restrict__ zsq,
    float* __restrict__ out_idx, int* __restrict__ idx_i,
    int* __restrict__ cnt, float* __restrict__ accum, int* __restrict__ flags)
{
    int tok = blockIdx.x * 256 + threadIdx.x;
    float d1 = 3.4e38f, d2 = 3.4e38f; int i1 = 0x7fffffff;
    #pragma unroll
    for (int nb = 0; nb < 8; ++nb) {
        float4 p = *(const float4*)&part[((size_t)tok * 8 + nb) * 4];
        float pd1 = p.x, pd2 = p.y; int pi1 = __float_as_int(p.z);
        if (pd1 < d1 || (pd1 == d1 && pi1 < i1)) { d2 = fminf(d1, pd2); d1 = pd1; i1 = pi1; }
        else d2 = fminf(d2, pd1);
    }
    out_idx[tok] = (float)i1;
    idx_i[tok] = i1;
    if (d2 - d1 < 0.01f) {
        int p = atomicAdd(cnt, 1);
        if (p >= 0 && p < NTOK) flags[p] = tok;
    }
    float c = zsq[tok] + d1;      // ||z||^2 + c_sq - 2 dot = ||z - q||^2
    __shared__ float red[256];
    red[threadIdx.x] = c; __syncthreads();
    for (int s = 128; s; s >>= 1) { if (threadIdx.x < s) red[threadIdx.x] += red[threadIdx.x + s]; __syncthreads(); }
    if (!threadIdx.x) atomicAdd(accum, red[0]);
}

// ---------------------------------------------------------------------------
// exact fp32 recompute of argmin for near-tie tokens.
// Round-5: wall time == one iteration's serial LATENCY (all ~nb blocks run in
// parallel). Round-3 was ~0-ILP on W loads (VALUBusy 1%); round-4's depth-1
// DMA dbuf stalled on vmcnt(0) at every barrier (worse). Now: explicit
// 4-stage REGISTER pipeline for W1/W2 (named stages, static indices) -> 12-16
// loads in flight, ~3 iterations of FMA+LDS latency cover per load. Identical
// per-(token,col) fma chains -> hs/zs bitwise identical to round-3.
// Dist phase: per-lane code ownership (thread t owns codes t, t+256) kills the
// per-(cc,tt) 6-level shuffle tree (6144 DS ops -> ~600); one argmin reduce at
// the end. Summation order differs (exact-fp32 path; order already differed
// from reference; sub-fp32-noise gaps don't occur in this input).
// ---------------------------------------------------------------------------
__device__ __forceinline__ void fma16(float (&a)[4][4],
    float x0, float x1, float x2, float x3, float4 w)
{
    a[0][0] = fmaf(x0, w.x, a[0][0]); a[0][1] = fmaf(x0, w.y, a[0][1]);
    a[0][2] = fmaf(x0, w.z, a[0][2]); a[0][3] = fmaf(x0, w.w, a[0][3]);
    a[1][0] = fmaf(x1, w.x, a[1][0]); a[1][1] = fmaf(x1, w.y, a[1][1]);
    a[1][2] = fmaf(x1, w.z, a[1][2]); a[1][3] = fmaf(x1, w.w, a[1][3]);
    a[2][0] = fmaf(x2, w.x, a[2][0]); a[2][1] = fmaf(x2, w.y, a[2][1]);
    a[2][2] = fmaf(x2, w.z, a[2][2]); a[2][3] = fmaf(x2, w.w, a[2][3]);
    a[3][0] = fmaf(x3, w.x, a[3][0]); a[3][1] = fmaf(x3, w.y, a[3][1]);
    a[3][2] = fmaf(x3, w.z, a[3][2]); a[3][3] = fmaf(x3, w.w, a[3][3]);
}
__device__ __forceinline__ void fma8(float (&a)[2][4],
    float x0, float x1, float4 w)
{
    a[0][0] = fmaf(x0, w.x, a[0][0]); a[0][1] = fmaf(x0, w.y, a[0][1]);
    a[0][2] = fmaf(x0, w.z, a[0][2]); a[0][3] = fmaf(x0, w.w, a[0][3]);
    a[1][0] = fmaf(x1, w.x, a[1][0]); a[1][1] = fmaf(x1, w.y, a[1][1]);
    a[1][2] = fmaf(x1, w.z, a[1][2]); a[1][3] = fmaf(x1, w.w, a[1][3]);
}

__global__ __launch_bounds__(256) void fixup(
    const int* __restrict__ cnt, const int* __restrict__ flags,
    const float* __restrict__ x, const float* __restrict__ W1, const float* __restrict__ b1,
    const float* __restrict__ W2, const float* __restrict__ b2,
    const float* __restrict__ cb, const float* __restrict__ csq,
    int* __restrict__ idx_i, float* __restrict__ out_idx)
{
    __shared__ float xs[8][IND];   // 24 KB
    __shared__ float hs[8][HID];   // 16 KB
    __shared__ float zs[8][CBD];   //  8 KB
    __shared__ float csq_s[CBS];   //  2 KB
    __shared__ float bd_s[4][8];
    __shared__ int   bi_s[4][8];
    __shared__ int   tok_s[8];

    int n = cnt[0]; if (n > NTOK) n = NTOK; if (n < 0) n = 0;
    const int t = threadIdx.x;
    const int nb = (n + 7) >> 3;

    if (t < 128) *(float4*)&csq_s[t * 4] = *(const float4*)(csq + t * 4);

    for (int ib = blockIdx.x; ib < nb; ib += gridDim.x) {
        const int base = ib * 8;
        __syncthreads();
        if (t < 8) {
            int fi = base + t; if (fi > n - 1) fi = n - 1;
            tok_s[t] = flags[fi];
        }
        __syncthreads();

        // stage 8 x-rows: 1536 float4, 6 per thread
        #pragma unroll
        for (int s = 0; s < 6; ++s) {
            int slot = t + s * 256;
            int tt = slot / 192, c4 = slot - tt * 192;
            *(float4*)&xs[tt][c4 * 4] =
                *(const float4*)(x + (size_t)tok_s[tt] * IND + c4 * 4);
        }
        __syncthreads();

        // ---- h = relu(x @ W1 + b1): thread owns 4 tokens x 4 cols,
        //      4-stage software-pipelined W loads ----
        {
            const int tg4 = (t >> 7) * 4;
            const int j0 = (t & 127) * 4;
            float a[4][4];
            float4 bb = *(const float4*)(b1 + j0);
            #pragma unroll
            for (int ti = 0; ti < 4; ++ti) {
                a[ti][0] = bb.x; a[ti][1] = bb.y; a[ti][2] = bb.z; a[ti][3] = bb.w;
            }
            const float* Wb = W1 + j0;
#define LW1(s, K4) { const int _k = (((K4) < 192) ? (K4) : 191) * 2048;        \
            s##0 = *(const float4*)(Wb + _k);                                  \
            s##1 = *(const float4*)(Wb + _k + 512);                            \
            s##2 = *(const float4*)(Wb + _k + 1024);                           \
            s##3 = *(const float4*)(Wb + _k + 1536); }
#define CMP1(s, K4) {                                                          \
            float4 xv0 = *(const float4*)&xs[tg4 + 0][(K4) * 4];               \
            float4 xv1 = *(const float4*)&xs[tg4 + 1][(K4) * 4];               \
            float4 xv2 = *(const float4*)&xs[tg4 + 2][(K4) * 4];               \
            float4 xv3 = *(const float4*)&xs[tg4 + 3][(K4) * 4];               \
            fma16(a, xv0.x, xv1.x, xv2.x, xv3.x, s##0);                        \
            fma16(a, xv0.y, xv1.y, xv2.y, xv3.y, s##1);                        \
            fma16(a, xv0.z, xv1.z, xv2.z, xv3.z, s##2);                        \
            fma16(a, xv0.w, xv1.w, xv2.w, xv3.w, s##3); }
            float4 wA0, wA1, wA2, wA3, wB0, wB1, wB2, wB3;
            float4 wC0, wC1, wC2, wC3, wD0, wD1, wD2, wD3;
            LW1(wA, 0); LW1(wB, 1); LW1(wC, 2);
            for (int k4 = 0; k4 < 192; k4 += 4) {
                LW1(wD, k4 + 3); CMP1(wA, k4 + 0);
                LW1(wA, k4 + 4); CMP1(wB, k4 + 1);
                LW1(wB, k4 + 5); CMP1(wC, k4 + 2);
                LW1(wC, k4 + 6); CMP1(wD, k4 + 3);
            }
#undef LW1
#undef CMP1
            #pragma unroll
            for (int ti = 0; ti < 4; ++ti) {
                float4 o = {fmaxf(a[ti][0], 0.f), fmaxf(a[ti][1], 0.f),
                            fmaxf(a[ti][2], 0.f), fmaxf(a[ti][3], 0.f)};
                *(float4*)&hs[tg4 + ti][j0] = o;
            }
        }
        __syncthreads();

        // ---- z = h @ W2 + b2: thread owns 2 tokens x 4 cols, same pipeline ----
        {
            const int tg2 = (t >> 6) * 2;
            const int c0 = (t & 63) * 4;
            float az[2][4];
            float4 bz = *(const float4*)(b2 + c0);
            #pragma unroll
            for (int ti = 0; ti < 2; ++ti) {
                az[ti][0] = bz.x; az[ti][1] = bz.y; az[ti][2] = bz.z; az[ti][3] = bz.w;
            }
            const float* Wb = W2 + c0;
#define LW2(s, K4) { const int _k = (((K4) < 128) ? (K4) : 127) * 1024;        \
            s##0 = *(const float4*)(Wb + _k);                                  \
            s##1 = *(const float4*)(Wb + _k + 256);                            \
            s##2 = *(const float4*)(Wb + _k + 512);                            \
            s##3 = *(const float4*)(Wb + _k + 768); }
#define CMP2(s, K4) {                                                          \
            float4 hv0 = *(const float4*)&hs[tg2 + 0][(K4) * 4];               \
            float4 hv1 = *(const float4*)&hs[tg2 + 1][(K4) * 4];               \
            fma8(az, hv0.x, hv1.x, s##0);                                      \
            fma8(az, hv0.y, hv1.y, s##1);                                      \
            fma8(az, hv0.z, hv1.z, s##2);                                      \
            fma8(az, hv0.w, hv1.w, s##3); }
            float4 wA0, wA1, wA2, wA3, wB0, wB1, wB2, wB3;
            float4 wC0, wC1, wC2, wC3, wD0, wD1, wD2, wD3;
            LW2(wA, 0); LW2(wB, 1); LW2(wC, 2);
            for (int k4 = 0; k4 < 128; k4 += 4) {
                LW2(wD, k4 + 3); CMP2(wA, k4 + 0);
                LW2(wA, k4 + 4); CMP2(wB, k4 + 1);
                LW2(wB, k4 + 5); CMP2(wC, k4 + 2);
                LW2(wC, k4 + 6); CMP2(wD, k4 + 3);
            }
#undef LW2
#undef CMP2
            #pragma unroll
            for (int ti = 0; ti < 2; ++ti) {
                float4 o = {az[ti][0], az[ti][1], az[ti][2], az[ti][3]};
                *(float4*)&zs[tg2 + ti][c0] = o;
            }
        }
        __syncthreads();

        // ---- dists + argmin: thread t owns codes t and t+256 ----
        {
            const int wv = t >> 6, l = t & 63;
            const float* cb0 = cb + (size_t)t * CBD;
            const float* cb1 = cb + (size_t)(t + 256) * CBD;
            float d0[8], d1[8];
            #pragma unroll
            for (int tt = 0; tt < 8; ++tt) { d0[tt] = 0.f; d1[tt] = 0.f; }
            float4 pA = *(const float4*)(cb0);
            float4 pB = *(const float4*)(cb1);
            for (int k4 = 0; k4 < 64; ++k4) {
                float4 cA = pA, cB = pB;
                int kn = (k4 + 1 < 64) ? (k4 + 1) : 63;
                pA = *(const float4*)(cb0 + kn * 4);
                pB = *(const float4*)(cb1 + kn * 4);
                #pragma unroll
                for (int tt = 0; tt < 8; ++tt) {
                    float4 zv = *(const float4*)&zs[tt][k4 * 4];
                    d0[tt] = fmaf(zv.w, cA.w, fmaf(zv.z, cA.z,
                             fmaf(zv.y, cA.y, fmaf(zv.x, cA.x, d0[tt]))));
                    d1[tt] = fmaf(zv.w, cB.w, fmaf(zv.z, cB.z,
                             fmaf(zv.y, cB.y, fmaf(zv.x, cB.x, d1[tt]))));
                }
            }
            float bd[8]; int bi[8];
            const float cs0 = csq_s[t], cs1 = csq_s[t + 256];
            #pragma unroll
            for (int tt = 0; tt < 8; ++tt) {
                float e0 = cs0 - 2.f * d0[tt];
                float e1 = cs1 - 2.f * d1[tt];
                if (e0 <= e1) { bd[tt] = e0; bi[tt] = t; }          // tie -> smaller idx
                else          { bd[tt] = e1; bi[tt] = t + 256; }
            }
            #pragma unroll
            for (int mm = 1; mm < 64; mm <<= 1) {
                #pragma unroll
                for (int tt = 0; tt < 8; ++tt) {
                    float od = __shfl_xor(bd[tt], mm, 64);
                    int   oi = __shfl_xor(bi[tt], mm, 64);
                    if (od < bd[tt] || (od == bd[tt] && oi < bi[tt])) { bd[tt] = od; bi[tt] = oi; }
                }
            }
            if (l == 0) {
                #pragma unroll
                for (int tt = 0; tt < 8; ++tt) { bd_s[wv][tt] = bd[tt]; bi_s[wv][tt] = bi[tt]; }
            }
        }
        __syncthreads();

        if (t < 8) {
            const int tt = t;
            float d = bd_s[0][tt]; int i = bi_s[0][tt];
            #pragma unroll
            for (int wv = 1; wv < 4; ++wv) {
                float od = bd_s[wv][tt]; int oi = bi_s[wv][tt];
                if (od < d || (od == d && oi < i)) { d = od; i = oi; }
            }
            if (base + tt < n) {
                int tok = tok_s[tt];
                idx_i[tok] = i; out_idx[tok] = (float)i;
            }
        }
        __syncthreads();
    }
}

// ---------------------------------------------------------------------------
// ReconTable = decoder(codebook): one block per code
// ---------------------------------------------------------------------------
__global__ __launch_bounds__(256) void table_pre(
    const float* __restrict__ cb, const float* __restrict__ W3,
    const float* __restrict__ b3, const float* __restrict__ W4,
    const float* __restrict__ b4, float* __restrict__ table)
{
    __shared__ float crow[CBD];
    __shared__ float h2[HID];
    const int c = blockIdx.x;
    const int t = threadIdx.x;
    crow[t] = cb[(size_t)c * CBD + t];
    __syncthreads();
    #pragma unroll
    for (int s = 0; s < 2; ++s) {
        int j = t + s * 256;
        float acc = b3[j];
        for (int k = 0; k < CBD; ++k) acc = fmaf(crow[k], W3[(size_t)k * HID + j], acc);
        h2[j] = fmaxf(acc, 0.f);
    }
    __syncthreads();
    #pragma unroll
    for (int s = 0; s < 3; ++s) {
        int j = t + s * 256;
        float acc = b4[j];
        for (int k = 0; k < HID; ++k) acc = fmaf(h2[k], W4[(size_t)k * IND + j], acc);
        table[(size_t)c * IND + j] = acc;
    }
}

// ---------------------------------------------------------------------------
// recon gather
// ---------------------------------------------------------------------------
__global__ __launch_bounds__(256) void gather_kernel(
    const int* __restrict__ idx, const float* __restrict__ table,
    float* __restrict__ out)
{
    unsigned i = blockIdx.x * 256u + threadIdx.x;   // float4 index, total NTOK*192
    unsigned tok = i / 192u;
    unsigned c = i - tok * 192u;
    int id = idx[tok];
    ((float4*)out)[i] = ((const float4*)table)[(size_t)id * 192 + c];
}

__global__ void finalize_kernel(const float* __restrict__ accum,
                                float* __restrict__ out_loss)
{
    out_loss[0] = accum[0] * (1.0f / 16777216.0f);   // mean over NTOK*CBD
}

// ---------------------------------------------------------------------------
extern "C" void kernel_launch(void* const* d_in, const int* in_sizes, int n_in,
                              void* d_out, int out_size, void* d_ws, size_t ws_size,
                              hipStream_t stream) {
    const float* x  = (const float*)d_in[0];
    const float* W1 = (const float*)d_in[1];
    const float* b1 = (const float*)d_in[2];
    const float* W2 = (const float*)d_in[3];
    const float* b2 = (const float*)d_in[4];
    const float* cb = (const float*)d_in[5];
    const float* W3 = (const float*)d_in[6];
    const float* b3 = (const float*)d_in[7];
    const float* W4 = (const float*)d_in[8];
    const float* b4 = (const float*)d_in[9];

    char* ws = (char*)d_ws;
    u32*  Hpk   = (u32*)(ws + OFF_H);
    u32*  Zpk   = (u32*)(ws + OFF_Z);
    u16*  W1h   = (u16*)(ws + OFF_W1H);
    u16*  W1l   = (u16*)(ws + OFF_W1L);
    u16*  W2h   = (u16*)(ws + OFF_W2H);
    u16*  W2l   = (u16*)(ws + OFF_W2L);
    u16*  CBh   = (u16*)(ws + OFF_CBH);
    u16*  CBl   = (u16*)(ws + OFF_CBL);
    float* csq  = (float*)(ws + OFF_CSQ);
    float* part = (float*)(ws + OFF_PART);
    float* table = (float*)(ws + OFF_TABLE);
    float* zsq  = (float*)(ws + OFF_ZSQ);
    int*   idx_i = (int*)(ws + OFF_IDX);
    int*   flags = (int*)(ws + OFF_FLAGS);
    int*   cnt   = (int*)(ws + OFF_CNT);
    float* accum = (float*)(ws + OFF_CNT + 4);

    float* out      = (float*)d_out;
    float* out_idx  = out + OUT_IDX_OFF;
    float* out_loss = out + OUT_LOSS_OFF;

    cbsplit<<<CBS, 256, 0, stream>>>(cb, CBh, CBl, csq);
    wsplit<<<HID, 256, 0, stream>>>(W1, W1h, W1l, IND, HID);   // W1T [512][768]
    wsplit<<<CBD, 256, 0, stream>>>(W2, W2h, W2l, HID, CBD);   // W2T [256][512]

    // h = relu(x @ W1 + b1) -> packed planes
    gemm3<0, 0><<<dim3(HID / 128, NTOK / 128), 256, 0, stream>>>(
        x, (const u32*)nullptr, W1h, W1l, b1, Hpk, (float*)nullptr, NTOK, HID, IND);
    // z = h @ W2 + b2 -> packed planes
    gemm3<1, 1><<<dim3(CBD / 128, NTOK / 128), 256, 0, stream>>>(
        (const float*)nullptr, Hpk, W2h, W2l, b2, Zpk, (float*)nullptr, NTOK, CBD, HID);

    // H region is dead from here on; zero cnt/accum AFTER GEMM1's Hpk writes
    hipMemsetAsync(cnt, 0, 8, stream);

    zsq_pk<<<NTOK / 4, 256, 0, stream>>>(Zpk, zsq);

    // dists top-2 partials: dist = c_sq - 2 * (z . c)
    gemm3<1, 2><<<dim3(CBS / 128, NTOK / 128), 256, 0, stream>>>(
        (const float*)nullptr, Zpk, CBh, CBl, csq, (u32*)nullptr, part, NTOK, CBS, CBD);

    table_pre<<<CBS, 256, 0, stream>>>(cb, W3, b3, W4, b4, table);

    vq_reduce<<<NTOK / 256, 256, 0, stream>>>(part, zsq, out_idx, idx_i, cnt, accum, flags);

    fixup<<<1024, 256, 0, stream>>>(cnt, flags, x, W1, b1, W2, b2, cb, csq, idx_i, out_idx);

    gather_kernel<<<(NTOK * (IND / 4)) / 256, 256, 0, stream>>>(idx_i, table, out);

    finalize_kernel<<<1, 1, 0, stream>>>(accum, out_loss);
}

// Round 6
// 875.557 us; speedup vs baseline: 1.2474x; 1.1112x over previous
//
#include <hip/hip_runtime.h>

typedef unsigned short u16;
typedef unsigned int   u32;
typedef __attribute__((ext_vector_type(8))) short short8;
typedef __attribute__((ext_vector_type(4))) float f32x4;

#define NTOK 65536
#define IND  768
#define HID  512
#define CBD  256
#define CBS  512

// d_out layout (floats): recon[NTOK*IND], indices-as-float[NTOK], loss[1]
#define OUT_IDX_OFF   ((size_t)NTOK * IND)
#define OUT_LOSS_OFF  (OUT_IDX_OFF + NTOK)

// ws byte offsets (packed u32 H/Z planes)
#define OFF_H      ((size_t)0)            // Hpack u32 [NTOK][HID]  = 134,217,728 B
#define OFF_Z      ((size_t)134217728)    // Zpack u32 [NTOK][CBD]  =  67,108,864 B
#define OFF_W1H    ((size_t)201326592)    // W1T hi u16 [HID][IND]
#define OFF_W1L    ((size_t)202113024)
#define OFF_W2H    ((size_t)202899456)    // W2T hi u16 [CBD][HID]
#define OFF_W2L    ((size_t)203161600)
#define OFF_CBH    ((size_t)203423744)    // CB  hi u16 [CBS][CBD]
#define OFF_CBL    ((size_t)203685888)
#define OFF_CSQ    ((size_t)203948032)    // c_sq f32 [CBS]
// aliases inside H region (H dead after GEMM2; Z dead after dist-GEMM+zsq)
#define OFF_PART   ((size_t)0)            // partials float4 [NTOK][8]
#define OFF_TABLE  ((size_t)8388608)      // ReconTable f32 [CBS][IND]
#define OFF_ZSQ    ((size_t)9961472)      // zsq f32 [NTOK]
#define OFF_IDX    ((size_t)10223616)     // idx int [NTOK]
#define OFF_FLAGS  ((size_t)10485760)     // flag list int [NTOK]
#define OFF_CNT    ((size_t)10747904)     // [0]=flag_count int, [4]=accum float
// fixup intermediates (chunked): h [32768][512] f32, z [32768][256] f32
#define OFF_HFIX   ((size_t)16777216)     // ends  83,886,080
#define OFF_ZFIX   ((size_t)83886080)     // ends 117,440,512  (< OFF_Z, inside dead H)
#define FCHUNK 32768

__device__ __forceinline__ u16 f2bf(float f) {
    u32 u = __float_as_uint(f);
    return (u16)((u + 0x7fffu + ((u >> 16) & 1u)) >> 16);
}
__device__ __forceinline__ float bf2f(u16 h) {
    return __uint_as_float(((u32)h) << 16);
}

// ---------------------------------------------------------------------------
// codebook split + c_sq : one block per code
// ---------------------------------------------------------------------------
__global__ __launch_bounds__(256) void cbsplit(
    const float* __restrict__ cb, u16* __restrict__ hi, u16* __restrict__ lo,
    float* __restrict__ csq)
{
    int c = blockIdx.x, t = threadIdx.x;
    float v = cb[(size_t)c * CBD + t];
    u16 h = f2bf(v); u16 l = f2bf(v - bf2f(h));
    hi[(size_t)c * CBD + t] = h; lo[(size_t)c * CBD + t] = l;
    __shared__ float red[256];
    red[t] = v * v; __syncthreads();
    for (int s = 128; s; s >>= 1) { if (t < s) red[t] += red[t + s]; __syncthreads(); }
    if (!t) csq[c] = red[0];
}

// ---------------------------------------------------------------------------
// weight transpose+split: W [K,N] fp32 -> WT hi/lo bf16 [N,K]. block per n.
// ---------------------------------------------------------------------------
__global__ __launch_bounds__(256) void wsplit(
    const float* __restrict__ W, u16* __restrict__ hi, u16* __restrict__ lo,
    int K, int N)
{
    int n = blockIdx.x;
    for (int k = threadIdx.x; k < K; k += 256) {
        float v = W[(size_t)k * N + n];
        u16 h = f2bf(v); u16 l = f2bf(v - bf2f(h));
        hi[(size_t)n * K + k] = h; lo[(size_t)n * K + k] = l;
    }
}

// ---------------------------------------------------------------------------
// bf16x3 MFMA GEMM (round-3 verified version, verbatim): 128x128 tile, BK=32,
// chunk-major LDS [chunk=k/8][row][8u16] stride 1040, bijective XCD swizzle.
// ---------------------------------------------------------------------------
#define CHS 1040   // u16 per chunk block: 128 rows * 8 + 8 pad
#define PLN (4 * CHS)

template<int AMODE, int EPI>
__global__ __launch_bounds__(256, 2) void gemm3(
    const float* __restrict__ Af, const u32* __restrict__ Apk,
    const u16* __restrict__ Bhi, const u16* __restrict__ Blo,
    const float* __restrict__ bias,
    u32* __restrict__ Opk, float* __restrict__ Opart,
    int M, int N, int K)
{
    __shared__ u16 lds[4 * PLN];              // 32.5 KB: Ahi, Alo, Bhi, Blo
    u16* sAh = lds;
    u16* sAl = lds + PLN;
    u16* sBh = lds + 2 * PLN;
    u16* sBl = lds + 3 * PLN;
    const int tid  = threadIdx.x;

    // XCD-aware bijective remap (all grids here have nwg % 8 == 0)
    const int nwg = gridDim.x * gridDim.y;
    const int hw  = blockIdx.y * gridDim.x + blockIdx.x;
    const int logical = (hw & 7) * (nwg >> 3) + (hw >> 3);
    const int bx = logical % gridDim.x;
    const int by = logical / gridDim.x;

    const int m0 = by * 128, n0 = bx * 128;
    const int w = tid >> 6, lane = tid & 63, quad = lane >> 4, l15 = lane & 15;
    const int wm = (w & 1) * 64, wn = (w >> 1) * 64;

    f32x4 acc[4][4] = {};

    for (int k0 = 0; k0 < K; k0 += 32) {
        __syncthreads();
        if (AMODE == 0) {
            #pragma unroll
            for (int s = 0; s < 4; ++s) {
                int slot = tid + s * 256;
                int m = slot >> 3, kg = (slot & 7) << 2;
                int c = kg >> 3, off = kg & 7;
                float4 v = *(const float4*)(Af + (size_t)(m0 + m) * K + k0 + kg);
                u16 h0 = f2bf(v.x), h1 = f2bf(v.y), h2 = f2bf(v.z), h3 = f2bf(v.w);
                ushort4 hv = {h0, h1, h2, h3};
                ushort4 lv = {f2bf(v.x - bf2f(h0)), f2bf(v.y - bf2f(h1)),
                              f2bf(v.z - bf2f(h2)), f2bf(v.w - bf2f(h3))};
                *(ushort4*)&sAh[c * CHS + m * 8 + off] = hv;
                *(ushort4*)&sAl[c * CHS + m * 8 + off] = lv;
            }
        } else {
            #pragma unroll
            for (int s = 0; s < 4; ++s) {
                int slot = tid + s * 256;
                int m = slot >> 3, ke = (slot & 7) << 2;   // 4 elems per uint4
                int c = ke >> 3, off = ke & 7;
                uint4 u = *(const uint4*)(Apk + (size_t)(m0 + m) * K + k0 + ke);
                ushort4 hv = {(u16)(u.x & 0xffff), (u16)(u.y & 0xffff),
                              (u16)(u.z & 0xffff), (u16)(u.w & 0xffff)};
                ushort4 lv = {(u16)(u.x >> 16), (u16)(u.y >> 16),
                              (u16)(u.z >> 16), (u16)(u.w >> 16)};
                *(ushort4*)&sAh[c * CHS + m * 8 + off] = hv;
                *(ushort4*)&sAl[c * CHS + m * 8 + off] = lv;
            }
        }
        // B planes [N,K] bf16 -> LDS (8 k-elems per uint4 = exactly one chunk row)
        #pragma unroll
        for (int s = 0; s < 4; ++s) {
            int slot = tid + s * 256;                 // 1024 slots, 512 per plane
            int n = (slot & 511) >> 2, ku = slot & 3; // ku = chunk
            const u16* src = (slot < 512) ? Bhi : Blo;
            u16* dst = (slot < 512) ? sBh : sBl;
            uint4 u = *(const uint4*)(src + (size_t)(n0 + n) * K + k0 + ku * 8);
            *(uint4*)&dst[ku * CHS + n * 8] = u;
        }
        __syncthreads();

        short8 ah[4], al[4], bh[4], bl[4];
        const int kc = quad * CHS;
        #pragma unroll
        for (int i = 0; i < 4; ++i) {
            int ar = wm + i * 16 + l15;
            int br = wn + i * 16 + l15;
            ah[i] = *(const short8*)&sAh[kc + ar * 8];
            al[i] = *(const short8*)&sAl[kc + ar * 8];
            bh[i] = *(const short8*)&sBh[kc + br * 8];
            bl[i] = *(const short8*)&sBl[kc + br * 8];
        }
        #pragma unroll
        for (int i = 0; i < 4; ++i)
            #pragma unroll
            for (int j = 0; j < 4; ++j) {
                acc[i][j] = __builtin_amdgcn_mfma_f32_16x16x32_bf16(ah[i], bh[j], acc[i][j], 0, 0, 0);
                acc[i][j] = __builtin_amdgcn_mfma_f32_16x16x32_bf16(ah[i], bl[j], acc[i][j], 0, 0, 0);
                acc[i][j] = __builtin_amdgcn_mfma_f32_16x16x32_bf16(al[i], bh[j], acc[i][j], 0, 0, 0);
            }
    }

    // epilogue. C/D layout: col = n-tile + l15, row = m-tile + quad*4 + r
    if (EPI <= 1) {
        float bn[4];
        #pragma unroll
        for (int j = 0; j < 4; ++j) bn[j] = bias[n0 + wn + j * 16 + l15];
        #pragma unroll
        for (int i = 0; i < 4; ++i)
            #pragma unroll
            for (int r = 0; r < 4; ++r) {
                int row = m0 + wm + i * 16 + quad * 4 + r;
                #pragma unroll
                for (int j = 0; j < 4; ++j) {
                    float v = acc[i][j][r] + bn[j];
                    if (EPI == 0) v = fmaxf(v, 0.f);
                    u16 h = f2bf(v); u16 l = f2bf(v - bf2f(h));
                    Opk[(size_t)row * N + n0 + wn + j * 16 + l15] = (u32)h | ((u32)l << 16);
                }
            }
    } else {
        float cs[4]; int cidx[4];
        #pragma unroll
        for (int j = 0; j < 4; ++j) {
            cidx[j] = n0 + wn + j * 16 + l15;
            cs[j] = bias[cidx[j]];
        }
        const int nparts = gridDim.x * 2;
        const int pslot  = bx * 2 + (w >> 1);   // distinct per wave-column!
        #pragma unroll
        for (int i = 0; i < 4; ++i)
            #pragma unroll
            for (int r = 0; r < 4; ++r) {
                int row = m0 + wm + i * 16 + quad * 4 + r;
                float d1 = 3.4e38f, d2 = 3.4e38f; int i1 = 0x7fffffff;
                #pragma unroll
                for (int j = 0; j < 4; ++j) {
                    float v = fmaf(-2.0f, acc[i][j][r], cs[j]);
                    if (v < d1) { d2 = d1; d1 = v; i1 = cidx[j]; }
                    else d2 = fminf(d2, v);
                }
                #pragma unroll
                for (int mm = 1; mm < 16; mm <<= 1) {
                    float od1 = __shfl_xor(d1, mm, 64);
                    float od2 = __shfl_xor(d2, mm, 64);
                    int   oi1 = __shfl_xor(i1, mm, 64);
                    if (od1 < d1 || (od1 == d1 && oi1 < i1)) { d2 = fminf(d1, od2); d1 = od1; i1 = oi1; }
                    else d2 = fminf(d2, od1);
                }
                if (l15 == 0) {
                    float4 o = {d1, d2, __int_as_float(i1), 0.f};
                    *(float4*)&Opart[((size_t)row * nparts + pslot) * 4] = o;
                }
            }
    }
}

// ---------------------------------------------------------------------------
// zsq from packed z
// ---------------------------------------------------------------------------
__global__ __launch_bounds__(256) void zsq_pk(
    const u32* __restrict__ Zpk, float* __restrict__ zsq)
{
    int tok = blockIdx.x * 4 + (threadIdx.x >> 6);
    int lane = threadIdx.x & 63;
    uint4 u = *(const uint4*)(Zpk + (size_t)tok * CBD + lane * 4);
    float z0 = bf2f((u16)(u.x & 0xffff)) + bf2f((u16)(u.x >> 16));
    float z1 = bf2f((u16)(u.y & 0xffff)) + bf2f((u16)(u.y >> 16));
    float z2 = bf2f((u16)(u.z & 0xffff)) + bf2f((u16)(u.z >> 16));
    float z3 = bf2f((u16)(u.w & 0xffff)) + bf2f((u16)(u.w >> 16));
    float s = z0 * z0 + z1 * z1 + z2 * z2 + z3 * z3;
    #pragma unroll
    for (int off = 32; off; off >>= 1) s += __shfl_down(s, off, 64);
    if (!lane) zsq[tok] = s;
}

// ---------------------------------------------------------------------------
// combine per-slot top2 partials (8 per token) -> idx, flags, commit sum
// ---------------------------------------------------------------------------
__global__ __launch_bounds__(256) void vq_reduce(
    const float* __restrict__ part, const float* __restrict__ zsq,
    float* __restrict__ out_idx, int* __restrict__ idx_i,
    int* __restrict__ cnt, float* __restrict__ accum, int* __restrict__ flags)
{
    int tok = blockIdx.x * 256 + threadIdx.x;
    float d1 = 3.4e38f, d2 = 3.4e38f; int i1 = 0x7fffffff;
    #pragma unroll
    for (int nb = 0; nb < 8; ++nb) {
        float4 p = *(const float4*)&part[((size_t)tok * 8 + nb) * 4];
        float pd1 = p.x, pd2 = p.y; int pi1 = __float_as_int(p.z);
        if (pd1 < d1 || (pd1 == d1 && pi1 < i1)) { d2 = fminf(d1, pd2); d1 = pd1; i1 = pi1; }
        else d2 = fminf(d2, pd1);
    }
    out_idx[tok] = (float)i1;
    idx_i[tok] = i1;
    if (d2 - d1 < 0.01f) {
        int p = atomicAdd(cnt, 1);
        if (p >= 0 && p < NTOK) flags[p] = tok;
    }
    float c = zsq[tok] + d1;      // ||z||^2 + c_sq - 2 dot = ||z - q||^2
    __shared__ float red[256];
    red[threadIdx.x] = c; __syncthreads();
    for (int s = 128; s; s >>= 1) { if (threadIdx.x < s) red[threadIdx.x] += red[threadIdx.x + s]; __syncthreads(); }
    if (!threadIdx.x) atomicAdd(accum, red[0]);
}

// ---------------------------------------------------------------------------
// fixup round-6: the monolithic kernel was aggregate-L2/L3-BW bound (every
// block streamed all of W1+W2+cb -> ~800MB at ~3TB/s = 270us regardless of
// pipelining). Split into 3 tiled kernels over the compacted flag list with
// intermediates in dead workspace: weight traffic drops ~9x (W read once per
// 64-token tile, not per 8-token block).
// Per-element numerics: init bias, serial ascending-k fma chain -> bitwise
// identical to round-5's h/z; dist/argmin code is round-5 verbatim.
// ---------------------------------------------------------------------------
__device__ __forceinline__ void fma16(float (&a)[4][4],
    float x0, float x1, float x2, float x3, float4 w)
{
    a[0][0] = fmaf(x0, w.x, a[0][0]); a[0][1] = fmaf(x0, w.y, a[0][1]);
    a[0][2] = fmaf(x0, w.z, a[0][2]); a[0][3] = fmaf(x0, w.w, a[0][3]);
    a[1][0] = fmaf(x1, w.x, a[1][0]); a[1][1] = fmaf(x1, w.y, a[1][1]);
    a[1][2] = fmaf(x1, w.z, a[1][2]); a[1][3] = fmaf(x1, w.w, a[1][3]);
    a[2][0] = fmaf(x2, w.x, a[2][0]); a[2][1] = fmaf(x2, w.y, a[2][1]);
    a[2][2] = fmaf(x2, w.z, a[2][2]); a[2][3] = fmaf(x2, w.w, a[2][3]);
    a[3][0] = fmaf(x3, w.x, a[3][0]); a[3][1] = fmaf(x3, w.y, a[3][1]);
    a[3][2] = fmaf(x3, w.z, a[3][2]); a[3][3] = fmaf(x3, w.w, a[3][3]);
}

// C[row][j] = act(A[row] . W[:,j] + b[j]) over 64-token x 64-col tiles.
// MODE 0: A row = x[flags[base+row]] (h phase). MODE 1: A row = A[trow+row]
// (z phase, contiguous chunk-local rows). K-chunks of 64 staged in LDS.
template<int K, int N, int RELU, int MODE>
__global__ __launch_bounds__(256) void fixup_gemm(
    const int* __restrict__ cnt, const int* __restrict__ flags, int base,
    const float* __restrict__ A, const float* __restrict__ W,
    const float* __restrict__ bias, float* __restrict__ C)
{
    __shared__ float xs[64][68];   // 17.4 KB (pad 68: bank-stripe)
    __shared__ float Wt[64][68];   // 17.4 KB
    __shared__ int   tok_s[64];
    int n = cnt[0]; if (n > NTOK) n = NTOK;
    int nc = n - base; if (nc <= 0) return; if (nc > FCHUNK) nc = FCHUNK;
    const int ntile = (nc + 63) >> 6;
    const int items = ntile * (N >> 6);
    const int t = threadIdx.x;
    const int tg4 = (t >> 4) << 2;   // token sub-row base (0,4,..,60)
    const int cg  = t & 15;          // col group (4 cols)

    for (int it = blockIdx.x; it < items; it += gridDim.x) {
        const int tt = it / (N >> 6);
        const int ct = it - tt * (N >> 6);
        const int j0 = ct * 64;
        const int trow = tt * 64;
        __syncthreads();                       // prev-iter readers done
        if (MODE == 0 && t < 64) {
            int fi = base + trow + t; if (fi > n - 1) fi = n - 1;
            tok_s[t] = flags[fi];
        }
        __syncthreads();

        float a[4][4];
        float4 bb = *(const float4*)(bias + j0 + cg * 4);
        #pragma unroll
        for (int ti = 0; ti < 4; ++ti) {
            a[ti][0] = bb.x; a[ti][1] = bb.y; a[ti][2] = bb.z; a[ti][3] = bb.w;
        }

        for (int k0 = 0; k0 < K; k0 += 64) {
            __syncthreads();
            // stage A 64 rows x 64 k (coalesced float4)
            #pragma unroll
            for (int s = 0; s < 4; ++s) {
                int slot = t + s * 256;
                int row = slot >> 4, c4 = slot & 15;
                const float* src = (MODE == 0)
                    ? A + (size_t)tok_s[row] * K + k0 + c4 * 4
                    : A + (size_t)(trow + row) * K + k0 + c4 * 4;
                *(float4*)&xs[row][c4 * 4] = *(const float4*)src;
            }
            // stage W 64 k x 64 cols (coalesced float4)
            #pragma unroll
            for (int s = 0; s < 4; ++s) {
                int slot = t + s * 256;
                int kk = slot >> 4, c4 = slot & 15;
                *(float4*)&Wt[kk][c4 * 4] =
                    *(const float4*)(W + (size_t)(k0 + kk) * N + j0 + c4 * 4);
            }
            __syncthreads();
            #pragma unroll 4
            for (int k4 = 0; k4 < 16; ++k4) {
                float4 xv0 = *(const float4*)&xs[tg4 + 0][k4 * 4];
                float4 xv1 = *(const float4*)&xs[tg4 + 1][k4 * 4];
                float4 xv2 = *(const float4*)&xs[tg4 + 2][k4 * 4];
                float4 xv3 = *(const float4*)&xs[tg4 + 3][k4 * 4];
                float4 w0 = *(const float4*)&Wt[k4 * 4 + 0][cg * 4];
                float4 w1 = *(const float4*)&Wt[k4 * 4 + 1][cg * 4];
                float4 w2 = *(const float4*)&Wt[k4 * 4 + 2][cg * 4];
                float4 w3 = *(const float4*)&Wt[k4 * 4 + 3][cg * 4];
                fma16(a, xv0.x, xv1.x, xv2.x, xv3.x, w0);
                fma16(a, xv0.y, xv1.y, xv2.y, xv3.y, w1);
                fma16(a, xv0.z, xv1.z, xv2.z, xv3.z, w2);
                fma16(a, xv0.w, xv1.w, xv2.w, xv3.w, w3);
            }
        }
        #pragma unroll
        for (int ti = 0; ti < 4; ++ti) {
            float4 o;
            if (RELU) {
                o.x = fmaxf(a[ti][0], 0.f); o.y = fmaxf(a[ti][1], 0.f);
                o.z = fmaxf(a[ti][2], 0.f); o.w = fmaxf(a[ti][3], 0.f);
            } else {
                o.x = a[ti][0]; o.y = a[ti][1]; o.z = a[ti][2]; o.w = a[ti][3];
            }
            *(float4*)&C[(size_t)(trow + tg4 + ti) * N + j0 + cg * 4] = o;
        }
    }
}

// dist + argmin over 32-token tiles; round-5 dist code verbatim per 8-token
// sub-batch (thread t owns codes t, t+256; butterfly argmin; same tie-breaks).
__global__ __launch_bounds__(256) void fixup_d(
    const int* __restrict__ cnt, const int* __restrict__ flags, int base,
    const float* __restrict__ zbuf, const float* __restrict__ cb,
    const float* __restrict__ csq,
    int* __restrict__ idx_i, float* __restrict__ out_idx)
{
    __shared__ float zs[32][CBD];   // 32 KB
    __shared__ float csq_s[CBS];    //  2 KB
    __shared__ float bd_s[4][8];
    __shared__ int   bi_s[4][8];
    int n = cnt[0]; if (n > NTOK) n = NTOK;
    int nc = n - base; if (nc <= 0) return; if (nc > FCHUNK) nc = FCHUNK;
    const int ntile = (nc + 31) >> 5;
    const int t = threadIdx.x;
    const int wv = t >> 6, l = t & 63;
    if (t < 128) *(float4*)&csq_s[t * 4] = *(const float4*)(csq + t * 4);

    for (int it = blockIdx.x; it < ntile; it += gridDim.x) {
        __syncthreads();
        #pragma unroll
        for (int s = 0; s < 8; ++s) {
            int slot = t + s * 256;
            int row = slot >> 6, c4 = slot & 63;
            *(float4*)&zs[row][c4 * 4] =
                *(const float4*)(zbuf + (size_t)(it * 32 + row) * CBD + c4 * 4);
        }
        __syncthreads();
        for (int sb = 0; sb < 4; ++sb) {
            const float* cb0 = cb + (size_t)t * CBD;
            const float* cb1 = cb + (size_t)(t + 256) * CBD;
            float d0[8], d1[8];
            #pragma unroll
            for (int tt = 0; tt < 8; ++tt) { d0[tt] = 0.f; d1[tt] = 0.f; }
            float4 pA = *(const float4*)(cb0);
            float4 pB = *(const float4*)(cb1);
            for (int k4 = 0; k4 < 64; ++k4) {
                float4 cA = pA, cB = pB;
                int kn = (k4 + 1 < 64) ? (k4 + 1) : 63;
                pA = *(const float4*)(cb0 + kn * 4);
                pB = *(const float4*)(cb1 + kn * 4);
                #pragma unroll
                for (int tt = 0; tt < 8; ++tt) {
                    float4 zv = *(const float4*)&zs[sb * 8 + tt][k4 * 4];
                    d0[tt] = fmaf(zv.w, cA.w, fmaf(zv.z, cA.z,
                             fmaf(zv.y, cA.y, fmaf(zv.x, cA.x, d0[tt]))));
                    d1[tt] = fmaf(zv.w, cB.w, fmaf(zv.z, cB.z,
                             fmaf(zv.y, cB.y, fmaf(zv.x, cB.x, d1[tt]))));
                }
            }
            float bd[8]; int bi[8];
            const float cs0 = csq_s[t], cs1 = csq_s[t + 256];
            #pragma unroll
            for (int tt = 0; tt < 8; ++tt) {
                float e0 = cs0 - 2.f * d0[tt];
                float e1 = cs1 - 2.f * d1[tt];
                if (e0 <= e1) { bd[tt] = e0; bi[tt] = t; }      // tie -> smaller idx
                else          { bd[tt] = e1; bi[tt] = t + 256; }
            }
            #pragma unroll
            for (int mm = 1; mm < 64; mm <<= 1) {
                #pragma unroll
                for (int tt = 0; tt < 8; ++tt) {
                    float od = __shfl_xor(bd[tt], mm, 64);
                    int   oi = __shfl_xor(bi[tt], mm, 64);
                    if (od < bd[tt] || (od == bd[tt] && oi < bi[tt])) { bd[tt] = od; bi[tt] = oi; }
                }
            }
            if (l == 0) {
                #pragma unroll
                for (int tt = 0; tt < 8; ++tt) { bd_s[wv][tt] = bd[tt]; bi_s[wv][tt] = bi[tt]; }
            }
            __syncthreads();
            if (t < 8) {
                const int tt = t;
                float d = bd_s[0][tt]; int i = bi_s[0][tt];
                #pragma unroll
                for (int v2 = 1; v2 < 4; ++v2) {
                    float od = bd_s[v2][tt]; int oi = bi_s[v2][tt];
                    if (od < d || (od == d && oi < i)) { d = od; i = oi; }
                }
                int fi = base + it * 32 + sb * 8 + tt;
                if (fi < n) {
                    int tok = flags[fi];
                    idx_i[tok] = i; out_idx[tok] = (float)i;
                }
            }
            __syncthreads();
        }
    }
}

// ---------------------------------------------------------------------------
// ReconTable = decoder(codebook): one block per code
// ---------------------------------------------------------------------------
__global__ __launch_bounds__(256) void table_pre(
    const float* __restrict__ cb, const float* __restrict__ W3,
    const float* __restrict__ b3, const float* __restrict__ W4,
    const float* __restrict__ b4, float* __restrict__ table)
{
    __shared__ float crow[CBD];
    __shared__ float h2[HID];
    const int c = blockIdx.x;
    const int t = threadIdx.x;
    crow[t] = cb[(size_t)c * CBD + t];
    __syncthreads();
    #pragma unroll
    for (int s = 0; s < 2; ++s) {
        int j = t + s * 256;
        float acc = b3[j];
        for (int k = 0; k < CBD; ++k) acc = fmaf(crow[k], W3[(size_t)k * HID + j], acc);
        h2[j] = fmaxf(acc, 0.f);
    }
    __syncthreads();
    #pragma unroll
    for (int s = 0; s < 3; ++s) {
        int j = t + s * 256;
        float acc = b4[j];
        for (int k = 0; k < HID; ++k) acc = fmaf(h2[k], W4[(size_t)k * IND + j], acc);
        table[(size_t)c * IND + j] = acc;
    }
}

// ---------------------------------------------------------------------------
// recon gather
// ---------------------------------------------------------------------------
__global__ __launch_bounds__(256) void gather_kernel(
    const int* __restrict__ idx, const float* __restrict__ table,
    float* __restrict__ out)
{
    unsigned i = blockIdx.x * 256u + threadIdx.x;   // float4 index, total NTOK*192
    unsigned tok = i / 192u;
    unsigned c = i - tok * 192u;
    int id = idx[tok];
    ((float4*)out)[i] = ((const float4*)table)[(size_t)id * 192 + c];
}

__global__ void finalize_kernel(const float* __restrict__ accum,
                                float* __restrict__ out_loss)
{
    out_loss[0] = accum[0] * (1.0f / 16777216.0f);   // mean over NTOK*CBD
}

// ---------------------------------------------------------------------------
extern "C" void kernel_launch(void* const* d_in, const int* in_sizes, int n_in,
                              void* d_out, int out_size, void* d_ws, size_t ws_size,
                              hipStream_t stream) {
    const float* x  = (const float*)d_in[0];
    const float* W1 = (const float*)d_in[1];
    const float* b1 = (const float*)d_in[2];
    const float* W2 = (const float*)d_in[3];
    const float* b2 = (const float*)d_in[4];
    const float* cb = (const float*)d_in[5];
    const float* W3 = (const float*)d_in[6];
    const float* b3 = (const float*)d_in[7];
    const float* W4 = (const float*)d_in[8];
    const float* b4 = (const float*)d_in[9];

    char* ws = (char*)d_ws;
    u32*  Hpk   = (u32*)(ws + OFF_H);
    u32*  Zpk   = (u32*)(ws + OFF_Z);
    u16*  W1h   = (u16*)(ws + OFF_W1H);
    u16*  W1l   = (u16*)(ws + OFF_W1L);
    u16*  W2h   = (u16*)(ws + OFF_W2H);
    u16*  W2l   = (u16*)(ws + OFF_W2L);
    u16*  CBh   = (u16*)(ws + OFF_CBH);
    u16*  CBl   = (u16*)(ws + OFF_CBL);
    float* csq  = (float*)(ws + OFF_CSQ);
    float* part = (float*)(ws + OFF_PART);
    float* table = (float*)(ws + OFF_TABLE);
    float* zsq  = (float*)(ws + OFF_ZSQ);
    int*   idx_i = (int*)(ws + OFF_IDX);
    int*   flags = (int*)(ws + OFF_FLAGS);
    int*   cnt   = (int*)(ws + OFF_CNT);
    float* accum = (float*)(ws + OFF_CNT + 4);
    float* hfix  = (float*)(ws + OFF_HFIX);
    float* zfix  = (float*)(ws + OFF_ZFIX);

    float* out      = (float*)d_out;
    float* out_idx  = out + OUT_IDX_OFF;
    float* out_loss = out + OUT_LOSS_OFF;

    cbsplit<<<CBS, 256, 0, stream>>>(cb, CBh, CBl, csq);
    wsplit<<<HID, 256, 0, stream>>>(W1, W1h, W1l, IND, HID);   // W1T [512][768]
    wsplit<<<CBD, 256, 0, stream>>>(W2, W2h, W2l, HID, CBD);   // W2T [256][512]

    // h = relu(x @ W1 + b1) -> packed planes
    gemm3<0, 0><<<dim3(HID / 128, NTOK / 128), 256, 0, stream>>>(
        x, (const u32*)nullptr, W1h, W1l, b1, Hpk, (float*)nullptr, NTOK, HID, IND);
    // z = h @ W2 + b2 -> packed planes
    gemm3<1, 1><<<dim3(CBD / 128, NTOK / 128), 256, 0, stream>>>(
        (const float*)nullptr, Hpk, W2h, W2l, b2, Zpk, (float*)nullptr, NTOK, CBD, HID);

    // H region is dead from here on; zero cnt/accum AFTER GEMM1's Hpk writes
    hipMemsetAsync(cnt, 0, 8, stream);

    zsq_pk<<<NTOK / 4, 256, 0, stream>>>(Zpk, zsq);

    // dists top-2 partials: dist = c_sq - 2 * (z . c)
    gemm3<1, 2><<<dim3(CBS / 128, NTOK / 128), 256, 0, stream>>>(
        (const float*)nullptr, Zpk, CBh, CBl, csq, (u32*)nullptr, part, NTOK, CBS, CBD);

    table_pre<<<CBS, 256, 0, stream>>>(cb, W3, b3, W4, b4, table);

    vq_reduce<<<NTOK / 256, 256, 0, stream>>>(part, zsq, out_idx, idx_i, cnt, accum, flags);

    // tiled exact-fp32 fixup, 2 chunks of 32768 flagged tokens (pass 2 idle
    // in the common case; its kernels early-exit on nc<=0)
    for (int pass = 0; pass < 2; ++pass) {
        int base = pass * FCHUNK;
        fixup_gemm<IND, HID, 1, 0><<<1024, 256, 0, stream>>>(
            cnt, flags, base, x, W1, b1, hfix);
        fixup_gemm<HID, CBD, 0, 1><<<512, 256, 0, stream>>>(
            cnt, flags, base, hfix, W2, b2, zfix);
        fixup_d<<<512, 256, 0, stream>>>(
            cnt, flags, base, zfix, cb, csq, idx_i, out_idx);
    }

    gather_kernel<<<(NTOK * (IND / 4)) / 256, 256, 0, stream>>>(idx_i, table, out);

    finalize_kernel<<<1, 1, 0, stream>>>(accum, out_loss);
}

// Round 7
// 851.296 us; speedup vs baseline: 1.2829x; 1.0285x over previous
//
#include <hip/hip_runtime.h>

typedef unsigned short u16;
typedef unsigned int   u32;
typedef __attribute__((ext_vector_type(8))) short short8;
typedef __attribute__((ext_vector_type(4))) float f32x4;

#define NTOK 65536
#define IND  768
#define HID  512
#define CBD  256
#define CBS  512

// d_out layout (floats): recon[NTOK*IND], indices-as-float[NTOK], loss[1]
#define OUT_IDX_OFF   ((size_t)NTOK * IND)
#define OUT_LOSS_OFF  (OUT_IDX_OFF + NTOK)

// ws layout (round-7): H and Z as SEPARATE hi/lo u16 planes so AMODE1 GEMMs
// stage A via global_load_lds DMA.
#define OFF_HH     ((size_t)0)            // H hi u16 [NTOK][HID] = 64MB
#define OFF_HL     ((size_t)67108864)     // H lo u16 [NTOK][HID] = 64MB
#define OFF_ZH     ((size_t)134217728)    // Z hi u16 [NTOK][CBD] = 32MB
#define OFF_ZL     ((size_t)167772160)    // Z lo u16 [NTOK][CBD] = 32MB
#define OFF_W1H    ((size_t)201326592)    // W1T hi u16 [HID][IND]
#define OFF_W1L    ((size_t)202113024)
#define OFF_W2H    ((size_t)202899456)    // W2T hi u16 [CBD][HID]
#define OFF_W2L    ((size_t)203161600)
#define OFF_CBH    ((size_t)203423744)    // CB  hi u16 [CBS][CBD]
#define OFF_CBL    ((size_t)203685888)
#define OFF_CSQ    ((size_t)203948032)    // c_sq f32 [CBS]
// aliases inside HH region (H planes dead after GEMM2; Z planes dead after
// dist-GEMM + zsq; all writers below run later in stream order)
#define OFF_PART   ((size_t)0)            // partials float4 [NTOK][8]
#define OFF_TABLE  ((size_t)8388608)      // ReconTable f32 [CBS][IND]
#define OFF_ZSQ    ((size_t)9961472)      // zsq f32 [NTOK]
#define OFF_IDX    ((size_t)10223616)     // idx int [NTOK]
#define OFF_FLAGS  ((size_t)10485760)     // flag list int [NTOK]
#define OFF_CNT    ((size_t)10747904)     // [0]=flag_count int, [4]=accum float
// fixup intermediates: span dead HH-tail + HL (both dead during fixup)
#define OFF_HFIX   ((size_t)16777216)     // h [32768][512] f32, ends 83,886,080
#define OFF_ZFIX   ((size_t)83886080)     // z [32768][256] f32, ends 117,440,512
#define FCHUNK 32768

__device__ __forceinline__ u16 f2bf(float f) {
    u32 u = __float_as_uint(f);
    return (u16)((u + 0x7fffu + ((u >> 16) & 1u)) >> 16);
}
__device__ __forceinline__ float bf2f(u16 h) {
    return __uint_as_float(((u32)h) << 16);
}

// async global->LDS DMA, 16B/lane. LDS dest = wave-uniform base + lane*16.
__device__ __forceinline__ void dma16(const void* g, void* l) {
    __builtin_amdgcn_global_load_lds(
        (const __attribute__((address_space(1))) u32*)g,
        (__attribute__((address_space(3))) u32*)l, 16, 0, 0);
}

// ---------------------------------------------------------------------------
// codebook split + c_sq : one block per code
// ---------------------------------------------------------------------------
__global__ __launch_bounds__(256) void cbsplit(
    const float* __restrict__ cb, u16* __restrict__ hi, u16* __restrict__ lo,
    float* __restrict__ csq)
{
    int c = blockIdx.x, t = threadIdx.x;
    float v = cb[(size_t)c * CBD + t];
    u16 h = f2bf(v); u16 l = f2bf(v - bf2f(h));
    hi[(size_t)c * CBD + t] = h; lo[(size_t)c * CBD + t] = l;
    __shared__ float red[256];
    red[t] = v * v; __syncthreads();
    for (int s = 128; s; s >>= 1) { if (t < s) red[t] += red[t + s]; __syncthreads(); }
    if (!t) csq[c] = red[0];
}

// ---------------------------------------------------------------------------
// weight transpose+split: W [K,N] fp32 -> WT hi/lo bf16 [N,K]. block per n.
// ---------------------------------------------------------------------------
__global__ __launch_bounds__(256) void wsplit(
    const float* __restrict__ W, u16* __restrict__ hi, u16* __restrict__ lo,
    int K, int N)
{
    int n = blockIdx.x;
    for (int k = threadIdx.x; k < K; k += 256) {
        float v = W[(size_t)k * N + n];
        u16 h = f2bf(v); u16 l = f2bf(v - bf2f(h));
        hi[(size_t)n * K + k] = h; lo[(size_t)n * K + k] = l;
    }
}

// ---------------------------------------------------------------------------
// bf16x3 MFMA GEMM: 128x128 tile, BK=32, 4 waves, 4x4 16x16x32 frags.
// Round-7: B (and AMODE1 A) staged via global_load_lds with 64B-segment
// coalesced source (4 lanes/row — same coalescing as the old register path;
// round-4's failure was 1 lane/row = 64-line gather) and source-side quad
// permutation quad' = quad ^ ((row>>1)&3), making fragment ds_read_b128
// 2-way (free). LDS linear [row][32 u16]/plane. Same (row,k) data in
// permuted slots -> bitwise-identical MFMA inputs.
// AMODE 0: A fp32 convert path (chunk-major CHS layout, unchanged); B-DMA
// issued FIRST so its latency hides under convert VALU.
// EPI 0/1: (relu) acc+bias -> hi/lo u16 planes.  EPI 2: dist top-2 partials.
// ---------------------------------------------------------------------------
#define CHS 1040   // u16 per A-chunk block (AMODE0): 128 rows * 8 + 8 pad

template<int AMODE, int EPI>
__global__ __launch_bounds__(256, 2) void gemm3(
    const float* __restrict__ Af,
    const u16* __restrict__ Ahi, const u16* __restrict__ Alo,
    const u16* __restrict__ Bhi, const u16* __restrict__ Blo,
    const float* __restrict__ bias,
    u16* __restrict__ Ohi, u16* __restrict__ Olo, float* __restrict__ Opart,
    int M, int N, int K)
{
    constexpr int APL = (AMODE == 0) ? 4160 : 4096;   // u16 per A plane
    __shared__ u16 lds[2 * 4160 + 2 * 4096];          // 33 KB max
    u16* sAh = lds;
    u16* sAl = lds + APL;
    u16* sBh = lds + 2 * APL;
    u16* sBl = lds + 2 * APL + 4096;
    const int tid  = threadIdx.x;

    // XCD-aware bijective remap (all grids here have nwg % 8 == 0)
    const int nwg = gridDim.x * gridDim.y;
    const int hw  = blockIdx.y * gridDim.x + blockIdx.x;
    const int logical = (hw & 7) * (nwg >> 3) + (hw >> 3);
    const int bx = logical % gridDim.x;
    const int by = logical / gridDim.x;

    const int m0 = by * 128, n0 = bx * 128;
    const int w = tid >> 6, lane = tid & 63, quad = lane >> 4, l15 = lane & 15;
    const int wm = (w & 1) * 64, wn = (w >> 1) * 64;
    const int dmarow = lane >> 2;                      // 4 lanes per row
    const int dmaq   = (lane & 3) ^ ((lane >> 3) & 3); // source quad permute
    const int fx     = (quad ^ ((l15 >> 1) & 3)) << 3; // read-side XOR (u16)

    f32x4 acc[4][4] = {};

    for (int k0 = 0; k0 < K; k0 += 32) {
        __syncthreads();
        // B planes: 16 wave-loads of 1KB (4/wave), async DMA
        #pragma unroll
        for (int g = 0; g < 4; ++g) {
            int wl = w * 4 + g;                        // 0..15
            int r0 = (wl & 7) << 4;
            const u16* P = (wl & 8) ? Blo : Bhi;
            u16* D = ((wl & 8) ? sBl : sBh) + r0 * 32;
            dma16(P + (size_t)(n0 + r0 + dmarow) * K + k0 + dmaq * 8, D);
        }
        if (AMODE == 1) {
            // A planes: same DMA mapping
            #pragma unroll
            for (int g = 0; g < 4; ++g) {
                int wl = w * 4 + g;
                int r0 = (wl & 7) << 4;
                const u16* P = (wl & 8) ? Alo : Ahi;
                u16* D = ((wl & 8) ? sAl : sAh) + r0 * 32;
                dma16(P + (size_t)(m0 + r0 + dmarow) * K + k0 + dmaq * 8, D);
            }
        } else {
            // A fp32 -> bf16 hi/lo convert staging (overlaps B DMA)
            #pragma unroll
            for (int s = 0; s < 4; ++s) {
                int slot = tid + s * 256;
                int m = slot >> 3, kg = (slot & 7) << 2;
                int c = kg >> 3, off = kg & 7;
                float4 v = *(const float4*)(Af + (size_t)(m0 + m) * K + k0 + kg);
                u16 h0 = f2bf(v.x), h1 = f2bf(v.y), h2 = f2bf(v.z), h3 = f2bf(v.w);
                ushort4 hv = {h0, h1, h2, h3};
                ushort4 lv = {f2bf(v.x - bf2f(h0)), f2bf(v.y - bf2f(h1)),
                              f2bf(v.z - bf2f(h2)), f2bf(v.w - bf2f(h3))};
                *(ushort4*)&sAh[c * CHS + m * 8 + off] = hv;
                *(ushort4*)&sAl[c * CHS + m * 8 + off] = lv;
            }
        }
        __syncthreads();

        short8 ah[4], al[4], bh[4], bl[4];
        #pragma unroll
        for (int i = 0; i < 4; ++i) {
            int ar = wm + i * 16 + l15;
            int br = wn + i * 16 + l15;
            if (AMODE == 0) {
                ah[i] = *(const short8*)&sAh[quad * CHS + ar * 8];
                al[i] = *(const short8*)&sAl[quad * CHS + ar * 8];
            } else {
                ah[i] = *(const short8*)&sAh[ar * 32 + fx];
                al[i] = *(const short8*)&sAl[ar * 32 + fx];
            }
            bh[i] = *(const short8*)&sBh[br * 32 + fx];
            bl[i] = *(const short8*)&sBl[br * 32 + fx];
        }
        #pragma unroll
        for (int i = 0; i < 4; ++i)
            #pragma unroll
            for (int j = 0; j < 4; ++j) {
                acc[i][j] = __builtin_amdgcn_mfma_f32_16x16x32_bf16(ah[i], bh[j], acc[i][j], 0, 0, 0);
                acc[i][j] = __builtin_amdgcn_mfma_f32_16x16x32_bf16(ah[i], bl[j], acc[i][j], 0, 0, 0);
                acc[i][j] = __builtin_amdgcn_mfma_f32_16x16x32_bf16(al[i], bh[j], acc[i][j], 0, 0, 0);
            }
    }

    // epilogue. C/D layout: col = n-tile + l15, row = m-tile + quad*4 + r
    if (EPI <= 1) {
        float bn[4];
        #pragma unroll
        for (int j = 0; j < 4; ++j) bn[j] = bias[n0 + wn + j * 16 + l15];
        #pragma unroll
        for (int i = 0; i < 4; ++i)
            #pragma unroll
            for (int r = 0; r < 4; ++r) {
                int row = m0 + wm + i * 16 + quad * 4 + r;
                #pragma unroll
                for (int j = 0; j < 4; ++j) {
                    float v = acc[i][j][r] + bn[j];
                    if (EPI == 0) v = fmaxf(v, 0.f);
                    u16 h = f2bf(v); u16 l = f2bf(v - bf2f(h));
                    size_t o = (size_t)row * N + n0 + wn + j * 16 + l15;
                    Ohi[o] = h; Olo[o] = l;
                }
            }
    } else {
        float cs[4]; int cidx[4];
        #pragma unroll
        for (int j = 0; j < 4; ++j) {
            cidx[j] = n0 + wn + j * 16 + l15;
            cs[j] = bias[cidx[j]];
        }
        const int nparts = gridDim.x * 2;
        const int pslot  = bx * 2 + (w >> 1);   // distinct per wave-column!
        #pragma unroll
        for (int i = 0; i < 4; ++i)
            #pragma unroll
            for (int r = 0; r < 4; ++r) {
                int row = m0 + wm + i * 16 + quad * 4 + r;
                float d1 = 3.4e38f, d2 = 3.4e38f; int i1 = 0x7fffffff;
                #pragma unroll
                for (int j = 0; j < 4; ++j) {
                    float v = fmaf(-2.0f, acc[i][j][r], cs[j]);
                    if (v < d1) { d2 = d1; d1 = v; i1 = cidx[j]; }
                    else d2 = fminf(d2, v);
                }
                #pragma unroll
                for (int mm = 1; mm < 16; mm <<= 1) {
                    float od1 = __shfl_xor(d1, mm, 64);
                    float od2 = __shfl_xor(d2, mm, 64);
                    int   oi1 = __shfl_xor(i1, mm, 64);
                    if (od1 < d1 || (od1 == d1 && oi1 < i1)) { d2 = fminf(d1, od2); d1 = od1; i1 = oi1; }
                    else d2 = fminf(d2, od1);
                }
                if (l15 == 0) {
                    float4 o = {d1, d2, __int_as_float(i1), 0.f};
                    *(float4*)&Opart[((size_t)row * nparts + pslot) * 4] = o;
                }
            }
    }
}

// ---------------------------------------------------------------------------
// zsq from hi/lo Z planes
// ---------------------------------------------------------------------------
__global__ __launch_bounds__(256) void zsq_pk(
    const u16* __restrict__ Zh, const u16* __restrict__ Zl, float* __restrict__ zsq)
{
    int tok = blockIdx.x * 4 + (threadIdx.x >> 6);
    int lane = threadIdx.x & 63;
    ushort4 uh = *(const ushort4*)(Zh + (size_t)tok * CBD + lane * 4);
    ushort4 ul = *(const ushort4*)(Zl + (size_t)tok * CBD + lane * 4);
    float z0 = bf2f(uh.x) + bf2f(ul.x);
    float z1 = bf2f(uh.y) + bf2f(ul.y);
    float z2 = bf2f(uh.z) + bf2f(ul.z);
    float z3 = bf2f(uh.w) + bf2f(ul.w);
    float s = z0 * z0 + z1 * z1 + z2 * z2 + z3 * z3;
    #pragma unroll
    for (int off = 32; off; off >>= 1) s += __shfl_down(s, off, 64);
    if (!lane) zsq[tok] = s;
}

// ---------------------------------------------------------------------------
// combine per-slot top2 partials (8 per token) -> idx, flags, commit sum
// ---------------------------------------------------------------------------
__global__ __launch_bounds__(256) void vq_reduce(
    const float* __restrict__ part, const float* __restrict__ zsq,
    float* __restrict__ out_idx, int* __restrict__ idx_i,
    int* __restrict__ cnt, float* __restrict__ accum, int* __restrict__ flags)
{
    int tok = blockIdx.x * 256 + threadIdx.x;
    float d1 = 3.4e38f, d2 = 3.4e38f; int i1 = 0x7fffffff;
    #pragma unroll
    for (int nb = 0; nb < 8; ++nb) {
        float4 p = *(const float4*)&part[((size_t)tok * 8 + nb) * 4];
        float pd1 = p.x, pd2 = p.y; int pi1 = __float_as_int(p.z);
        if (pd1 < d1 || (pd1 == d1 && pi1 < i1)) { d2 = fminf(d1, pd2); d1 = pd1; i1 = pi1; }
        else d2 = fminf(d2, pd1);
    }
    out_idx[tok] = (float)i1;
    idx_i[tok] = i1;
    if (d2 - d1 < 0.01f) {
        int p = atomicAdd(cnt, 1);
        if (p >= 0 && p < NTOK) flags[p] = tok;
    }
    float c = zsq[tok] + d1;      // ||z||^2 + c_sq - 2 dot = ||z - q||^2
    __shared__ float red[256];
    red[threadIdx.x] = c; __syncthreads();
    for (int s = 128; s; s >>= 1) { if (threadIdx.x < s) red[threadIdx.x] += red[threadIdx.x + s]; __syncthreads(); }
    if (!threadIdx.x) atomicAdd(accum, red[0]);
}

// ---------------------------------------------------------------------------
// tiled exact-fp32 fixup (round-6 verified structure, verbatim)
// ---------------------------------------------------------------------------
__device__ __forceinline__ void fma16(float (&a)[4][4],
    float x0, float x1, float x2, float x3, float4 w)
{
    a[0][0] = fmaf(x0, w.x, a[0][0]); a[0][1] = fmaf(x0, w.y, a[0][1]);
    a[0][2] = fmaf(x0, w.z, a[0][2]); a[0][3] = fmaf(x0, w.w, a[0][3]);
    a[1][0] = fmaf(x1, w.x, a[1][0]); a[1][1] = fmaf(x1, w.y, a[1][1]);
    a[1][2] = fmaf(x1, w.z, a[1][2]); a[1][3] = fmaf(x1, w.w, a[1][3]);
    a[2][0] = fmaf(x2, w.x, a[2][0]); a[2][1] = fmaf(x2, w.y, a[2][1]);
    a[2][2] = fmaf(x2, w.z, a[2][2]); a[2][3] = fmaf(x2, w.w, a[2][3]);
    a[3][0] = fmaf(x3, w.x, a[3][0]); a[3][1] = fmaf(x3, w.y, a[3][1]);
    a[3][2] = fmaf(x3, w.z, a[3][2]); a[3][3] = fmaf(x3, w.w, a[3][3]);
}

template<int K, int N, int RELU, int MODE>
__global__ __launch_bounds__(256) void fixup_gemm(
    const int* __restrict__ cnt, const int* __restrict__ flags, int base,
    const float* __restrict__ A, const float* __restrict__ W,
    const float* __restrict__ bias, float* __restrict__ C)
{
    __shared__ float xs[64][68];
    __shared__ float Wt[64][68];
    __shared__ int   tok_s[64];
    int n = cnt[0]; if (n > NTOK) n = NTOK;
    int nc = n - base; if (nc <= 0) return; if (nc > FCHUNK) nc = FCHUNK;
    const int ntile = (nc + 63) >> 6;
    const int items = ntile * (N >> 6);
    const int t = threadIdx.x;
    const int tg4 = (t >> 4) << 2;
    const int cg  = t & 15;

    for (int it = blockIdx.x; it < items; it += gridDim.x) {
        const int tt = it / (N >> 6);
        const int ct = it - tt * (N >> 6);
        const int j0 = ct * 64;
        const int trow = tt * 64;
        __syncthreads();
        if (MODE == 0 && t < 64) {
            int fi = base + trow + t; if (fi > n - 1) fi = n - 1;
            tok_s[t] = flags[fi];
        }
        __syncthreads();

        float a[4][4];
        float4 bb = *(const float4*)(bias + j0 + cg * 4);
        #pragma unroll
        for (int ti = 0; ti < 4; ++ti) {
            a[ti][0] = bb.x; a[ti][1] = bb.y; a[ti][2] = bb.z; a[ti][3] = bb.w;
        }

        for (int k0 = 0; k0 < K; k0 += 64) {
            __syncthreads();
            #pragma unroll
            for (int s = 0; s < 4; ++s) {
                int slot = t + s * 256;
                int row = slot >> 4, c4 = slot & 15;
                const float* src = (MODE == 0)
                    ? A + (size_t)tok_s[row] * K + k0 + c4 * 4
                    : A + (size_t)(trow + row) * K + k0 + c4 * 4;
                *(float4*)&xs[row][c4 * 4] = *(const float4*)src;
            }
            #pragma unroll
            for (int s = 0; s < 4; ++s) {
                int slot = t + s * 256;
                int kk = slot >> 4, c4 = slot & 15;
                *(float4*)&Wt[kk][c4 * 4] =
                    *(const float4*)(W + (size_t)(k0 + kk) * N + j0 + c4 * 4);
            }
            __syncthreads();
            #pragma unroll 4
            for (int k4 = 0; k4 < 16; ++k4) {
                float4 xv0 = *(const float4*)&xs[tg4 + 0][k4 * 4];
                float4 xv1 = *(const float4*)&xs[tg4 + 1][k4 * 4];
                float4 xv2 = *(const float4*)&xs[tg4 + 2][k4 * 4];
                float4 xv3 = *(const float4*)&xs[tg4 + 3][k4 * 4];
                float4 w0 = *(const float4*)&Wt[k4 * 4 + 0][cg * 4];
                float4 w1 = *(const float4*)&Wt[k4 * 4 + 1][cg * 4];
                float4 w2 = *(const float4*)&Wt[k4 * 4 + 2][cg * 4];
                float4 w3 = *(const float4*)&Wt[k4 * 4 + 3][cg * 4];
                fma16(a, xv0.x, xv1.x, xv2.x, xv3.x, w0);
                fma16(a, xv0.y, xv1.y, xv2.y, xv3.y, w1);
                fma16(a, xv0.z, xv1.z, xv2.z, xv3.z, w2);
                fma16(a, xv0.w, xv1.w, xv2.w, xv3.w, w3);
            }
        }
        #pragma unroll
        for (int ti = 0; ti < 4; ++ti) {
            float4 o;
            if (RELU) {
                o.x = fmaxf(a[ti][0], 0.f); o.y = fmaxf(a[ti][1], 0.f);
                o.z = fmaxf(a[ti][2], 0.f); o.w = fmaxf(a[ti][3], 0.f);
            } else {
                o.x = a[ti][0]; o.y = a[ti][1]; o.z = a[ti][2]; o.w = a[ti][3];
            }
            *(float4*)&C[(size_t)(trow + tg4 + ti) * N + j0 + cg * 4] = o;
        }
    }
}

__global__ __launch_bounds__(256) void fixup_d(
    const int* __restrict__ cnt, const int* __restrict__ flags, int base,
    const float* __restrict__ zbuf, const float* __restrict__ cb,
    const float* __restrict__ csq,
    int* __restrict__ idx_i, float* __restrict__ out_idx)
{
    __shared__ float zs[32][CBD];
    __shared__ float csq_s[CBS];
    __shared__ float bd_s[4][8];
    __shared__ int   bi_s[4][8];
    int n = cnt[0]; if (n > NTOK) n = NTOK;
    int nc = n - base; if (nc <= 0) return; if (nc > FCHUNK) nc = FCHUNK;
    const int ntile = (nc + 31) >> 5;
    const int t = threadIdx.x;
    const int wv = t >> 6, l = t & 63;
    if (t < 128) *(float4*)&csq_s[t * 4] = *(const float4*)(csq + t * 4);

    for (int it = blockIdx.x; it < ntile; it += gridDim.x) {
        __syncthreads();
        #pragma unroll
        for (int s = 0; s < 8; ++s) {
            int slot = t + s * 256;
            int row = slot >> 6, c4 = slot & 63;
            *(float4*)&zs[row][c4 * 4] =
                *(const float4*)(zbuf + (size_t)(it * 32 + row) * CBD + c4 * 4);
        }
        __syncthreads();
        for (int sb = 0; sb < 4; ++sb) {
            const float* cb0 = cb + (size_t)t * CBD;
            const float* cb1 = cb + (size_t)(t + 256) * CBD;
            float d0[8], d1[8];
            #pragma unroll
            for (int tt = 0; tt < 8; ++tt) { d0[tt] = 0.f; d1[tt] = 0.f; }
            float4 pA = *(const float4*)(cb0);
            float4 pB = *(const float4*)(cb1);
            for (int k4 = 0; k4 < 64; ++k4) {
                float4 cA = pA, cB = pB;
                int kn = (k4 + 1 < 64) ? (k4 + 1) : 63;
                pA = *(const float4*)(cb0 + kn * 4);
                pB = *(const float4*)(cb1 + kn * 4);
                #pragma unroll
                for (int tt = 0; tt < 8; ++tt) {
                    float4 zv = *(const float4*)&zs[sb * 8 + tt][k4 * 4];
                    d0[tt] = fmaf(zv.w, cA.w, fmaf(zv.z, cA.z,
                             fmaf(zv.y, cA.y, fmaf(zv.x, cA.x, d0[tt]))));
                    d1[tt] = fmaf(zv.w, cB.w, fmaf(zv.z, cB.z,
                             fmaf(zv.y, cB.y, fmaf(zv.x, cB.x, d1[tt]))));
                }
            }
            float bd[8]; int bi[8];
            const float cs0 = csq_s[t], cs1 = csq_s[t + 256];
            #pragma unroll
            for (int tt = 0; tt < 8; ++tt) {
                float e0 = cs0 - 2.f * d0[tt];
                float e1 = cs1 - 2.f * d1[tt];
                if (e0 <= e1) { bd[tt] = e0; bi[tt] = t; }      // tie -> smaller idx
                else          { bd[tt] = e1; bi[tt] = t + 256; }
            }
            #pragma unroll
            for (int mm = 1; mm < 64; mm <<= 1) {
                #pragma unroll
                for (int tt = 0; tt < 8; ++tt) {
                    float od = __shfl_xor(bd[tt], mm, 64);
                    int   oi = __shfl_xor(bi[tt], mm, 64);
                    if (od < bd[tt] || (od == bd[tt] && oi < bi[tt])) { bd[tt] = od; bi[tt] = oi; }
                }
            }
            if (l == 0) {
                #pragma unroll
                for (int tt = 0; tt < 8; ++tt) { bd_s[wv][tt] = bd[tt]; bi_s[wv][tt] = bi[tt]; }
            }
            __syncthreads();
            if (t < 8) {
                const int tt = t;
                float d = bd_s[0][tt]; int i = bi_s[0][tt];
                #pragma unroll
                for (int v2 = 1; v2 < 4; ++v2) {
                    float od = bd_s[v2][tt]; int oi = bi_s[v2][tt];
                    if (od < d || (od == d && oi < i)) { d = od; i = oi; }
                }
                int fi = base + it * 32 + sb * 8 + tt;
                if (fi < n) {
                    int tok = flags[fi];
                    idx_i[tok] = i; out_idx[tok] = (float)i;
                }
            }
            __syncthreads();
        }
    }
}

// ---------------------------------------------------------------------------
// ReconTable = decoder(codebook): one block per code
// ---------------------------------------------------------------------------
__global__ __launch_bounds__(256) void table_pre(
    const float* __restrict__ cb, const float* __restrict__ W3,
    const float* __restrict__ b3, const float* __restrict__ W4,
    const float* __restrict__ b4, float* __restrict__ table)
{
    __shared__ float crow[CBD];
    __shared__ float h2[HID];
    const int c = blockIdx.x;
    const int t = threadIdx.x;
    crow[t] = cb[(size_t)c * CBD + t];
    __syncthreads();
    #pragma unroll
    for (int s = 0; s < 2; ++s) {
        int j = t + s * 256;
        float acc = b3[j];
        for (int k = 0; k < CBD; ++k) acc = fmaf(crow[k], W3[(size_t)k * HID + j], acc);
        h2[j] = fmaxf(acc, 0.f);
    }
    __syncthreads();
    #pragma unroll
    for (int s = 0; s < 3; ++s) {
        int j = t + s * 256;
        float acc = b4[j];
        for (int k = 0; k < HID; ++k) acc = fmaf(h2[k], W4[(size_t)k * IND + j], acc);
        table[(size_t)c * IND + j] = acc;
    }
}

// ---------------------------------------------------------------------------
// recon gather
// ---------------------------------------------------------------------------
__global__ __launch_bounds__(256) void gather_kernel(
    const int* __restrict__ idx, const float* __restrict__ table,
    float* __restrict__ out)
{
    unsigned i = blockIdx.x * 256u + threadIdx.x;   // float4 index, total NTOK*192
    unsigned tok = i / 192u;
    unsigned c = i - tok * 192u;
    int id = idx[tok];
    ((float4*)out)[i] = ((const float4*)table)[(size_t)id * 192 + c];
}

__global__ void finalize_kernel(const float* __restrict__ accum,
                                float* __restrict__ out_loss)
{
    out_loss[0] = accum[0] * (1.0f / 16777216.0f);   // mean over NTOK*CBD
}

// ---------------------------------------------------------------------------
extern "C" void kernel_launch(void* const* d_in, const int* in_sizes, int n_in,
                              void* d_out, int out_size, void* d_ws, size_t ws_size,
                              hipStream_t stream) {
    const float* x  = (const float*)d_in[0];
    const float* W1 = (const float*)d_in[1];
    const float* b1 = (const float*)d_in[2];
    const float* W2 = (const float*)d_in[3];
    const float* b2 = (const float*)d_in[4];
    const float* cb = (const float*)d_in[5];
    const float* W3 = (const float*)d_in[6];
    const float* b3 = (const float*)d_in[7];
    const float* W4 = (const float*)d_in[8];
    const float* b4 = (const float*)d_in[9];

    char* ws = (char*)d_ws;
    u16*  Hh    = (u16*)(ws + OFF_HH);
    u16*  Hl    = (u16*)(ws + OFF_HL);
    u16*  Zh    = (u16*)(ws + OFF_ZH);
    u16*  Zl    = (u16*)(ws + OFF_ZL);
    u16*  W1h   = (u16*)(ws + OFF_W1H);
    u16*  W1l   = (u16*)(ws + OFF_W1L);
    u16*  W2h   = (u16*)(ws + OFF_W2H);
    u16*  W2l   = (u16*)(ws + OFF_W2L);
    u16*  CBh   = (u16*)(ws + OFF_CBH);
    u16*  CBl   = (u16*)(ws + OFF_CBL);
    float* csq  = (float*)(ws + OFF_CSQ);
    float* part = (float*)(ws + OFF_PART);
    float* table = (float*)(ws + OFF_TABLE);
    float* zsq  = (float*)(ws + OFF_ZSQ);
    int*   idx_i = (int*)(ws + OFF_IDX);
    int*   flags = (int*)(ws + OFF_FLAGS);
    int*   cnt   = (int*)(ws + OFF_CNT);
    float* accum = (float*)(ws + OFF_CNT + 4);
    float* hfix  = (float*)(ws + OFF_HFIX);
    float* zfix  = (float*)(ws + OFF_ZFIX);

    float* out      = (float*)d_out;
    float* out_idx  = out + OUT_IDX_OFF;
    float* out_loss = out + OUT_LOSS_OFF;

    cbsplit<<<CBS, 256, 0, stream>>>(cb, CBh, CBl, csq);
    wsplit<<<HID, 256, 0, stream>>>(W1, W1h, W1l, IND, HID);   // W1T [512][768]
    wsplit<<<CBD, 256, 0, stream>>>(W2, W2h, W2l, HID, CBD);   // W2T [256][512]

    // h = relu(x @ W1 + b1) -> hi/lo planes
    gemm3<0, 0><<<dim3(HID / 128, NTOK / 128), 256, 0, stream>>>(
        x, (const u16*)nullptr, (const u16*)nullptr, W1h, W1l, b1,
        Hh, Hl, (float*)nullptr, NTOK, HID, IND);
    // z = h @ W2 + b2 -> hi/lo planes
    gemm3<1, 1><<<dim3(CBD / 128, NTOK / 128), 256, 0, stream>>>(
        (const float*)nullptr, Hh, Hl, W2h, W2l, b2,
        Zh, Zl, (float*)nullptr, NTOK, CBD, HID);

    // H planes dead from here on; zero cnt/accum AFTER GEMM2 consumed them
    hipMemsetAsync(cnt, 0, 8, stream);

    zsq_pk<<<NTOK / 4, 256, 0, stream>>>(Zh, Zl, zsq);

    // dists top-2 partials: dist = c_sq - 2 * (z . c)
    gemm3<1, 2><<<dim3(CBS / 128, NTOK / 128), 256, 0, stream>>>(
        (const float*)nullptr, Zh, Zl, CBh, CBl, csq,
        (u16*)nullptr, (u16*)nullptr, part, NTOK, CBS, CBD);

    table_pre<<<CBS, 256, 0, stream>>>(cb, W3, b3, W4, b4, table);

    vq_reduce<<<NTOK / 256, 256, 0, stream>>>(part, zsq, out_idx, idx_i, cnt, accum, flags);

    // tiled exact-fp32 fixup, 2 chunks of 32768 flagged tokens
    for (int pass = 0; pass < 2; ++pass) {
        int base = pass * FCHUNK;
        fixup_gemm<IND, HID, 1, 0><<<1024, 256, 0, stream>>>(
            cnt, flags, base, x, W1, b1, hfix);
        fixup_gemm<HID, CBD, 0, 1><<<512, 256, 0, stream>>>(
            cnt, flags, base, hfix, W2, b2, zfix);
        fixup_d<<<512, 256, 0, stream>>>(
            cnt, flags, base, zfix, cb, csq, idx_i, out_idx);
    }

    gather_kernel<<<(NTOK * (IND / 4)) / 256, 256, 0, stream>>>(idx_i, table, out);

    finalize_kernel<<<1, 1, 0, stream>>>(accum, out_loss);
}